// Round 1
// baseline (395.749 us; speedup 1.0000x reference)
//
#include <hip/hip_runtime.h>
#include <hip/hip_bf16.h>

// Problem constants: B=4, T=2048, C=1024, H=16, D=64
#define BATCH 4
#define SEQ   2048
#define CH    1024
#define NH    16
#define HD    64
#define BT    8192   // BATCH*SEQ

typedef __attribute__((ext_vector_type(8))) short bf16x8;
typedef __attribute__((ext_vector_type(4))) float f32x4;

__device__ __forceinline__ unsigned short f2b(float f) {
  __hip_bfloat16 h = __float2bfloat16(f);
  return *reinterpret_cast<unsigned short*>(&h);
}

// ---------------- conversion kernels ----------------

__global__ void conv_x_bf16(const float* __restrict__ in, unsigned short* __restrict__ out, int n4) {
  int i = blockIdx.x * blockDim.x + threadIdx.x;
  if (i >= n4) return;
  float4 v = reinterpret_cast<const float4*>(in)[i];
  ushort4 o;
  o.x = f2b(v.x); o.y = f2b(v.y); o.z = f2b(v.z); o.w = f2b(v.w);
  reinterpret_cast<ushort4*>(out)[i] = o;
}

// in[R][Cc] f32  ->  out[Cc][R] bf16
__global__ void transpose_w_bf16(const float* __restrict__ in, unsigned short* __restrict__ out,
                                 int R, int Cc) {
  __shared__ float tile[32][33];
  int c0 = blockIdx.x * 32, r0 = blockIdx.y * 32;
  int tx = threadIdx.x, ty = threadIdx.y;
  #pragma unroll
  for (int i = 0; i < 32; i += 8)
    tile[ty + i][tx] = in[(size_t)(r0 + ty + i) * Cc + c0 + tx];
  __syncthreads();
  #pragma unroll
  for (int i = 0; i < 32; i += 8)
    out[(size_t)(c0 + ty + i) * R + r0 + tx] = f2b(tile[tx][ty + i]);
}

// ---------------- GEMM1: qkv = x @ w_attn + b, scatter to Q/K/Vt ----------------
// A  [8192][1024] bf16, BT(w_attn^T) [3072][1024] bf16
// Q,K: [B*H][T][D] bf16 ; Vt: [B*H][D][T] bf16

__global__ __launch_bounds__(256) void gemm_qkv(
    const unsigned short* __restrict__ A,
    const unsigned short* __restrict__ Bt,
    const float* __restrict__ bias,
    unsigned short* __restrict__ Qb,
    unsigned short* __restrict__ Kb,
    unsigned short* __restrict__ Vt) {
  constexpr int K = 1024;
  __shared__ __align__(16) unsigned short As[128 * 32];
  __shared__ __align__(16) unsigned short Bs[128 * 32];
  int tid = threadIdx.x;
  int lane = tid & 63, wav = tid >> 6;
  int wr = wav >> 1, wc = wav & 1;
  int lr = lane & 15, lh = lane >> 4;
  int wbase = tid & 192;
  int m0 = blockIdx.x * 128, n0 = blockIdx.y * 128;

  f32x4 acc[4][4];
  #pragma unroll
  for (int i = 0; i < 4; ++i)
    #pragma unroll
    for (int j = 0; j < 4; ++j)
      acc[i][j] = f32x4{0.f, 0.f, 0.f, 0.f};

  for (int k0 = 0; k0 < K; k0 += 32) {
    #pragma unroll
    for (int c = 0; c < 2; ++c) {
      int idx = c * 256 + tid;
      const unsigned short* srcA = A + (size_t)(m0 + (idx >> 2)) * K + k0 + (idx & 3) * 8;
      __builtin_amdgcn_global_load_lds((const __attribute__((address_space(1))) void*)srcA,
          (__attribute__((address_space(3))) void*)&As[(c * 256 + wbase) * 8], 16, 0, 0);
      const unsigned short* srcB = Bt + (size_t)(n0 + (idx >> 2)) * K + k0 + (idx & 3) * 8;
      __builtin_amdgcn_global_load_lds((const __attribute__((address_space(1))) void*)srcB,
          (__attribute__((address_space(3))) void*)&Bs[(c * 256 + wbase) * 8], 16, 0, 0);
    }
    __syncthreads();
    bf16x8 a[4], b[4];
    #pragma unroll
    for (int i = 0; i < 4; ++i)
      a[i] = *reinterpret_cast<const bf16x8*>(&As[(wr * 64 + i * 16 + lr) * 32 + lh * 8]);
    #pragma unroll
    for (int j = 0; j < 4; ++j)
      b[j] = *reinterpret_cast<const bf16x8*>(&Bs[(wc * 64 + j * 16 + lr) * 32 + lh * 8]);
    #pragma unroll
    for (int i = 0; i < 4; ++i)
      #pragma unroll
      for (int j = 0; j < 4; ++j)
        acc[i][j] = __builtin_amdgcn_mfma_f32_16x16x32_bf16(a[i], b[j], acc[i][j], 0, 0, 0);
    __syncthreads();
  }

  #pragma unroll
  for (int i = 0; i < 4; ++i) {
    #pragma unroll
    for (int j = 0; j < 4; ++j) {
      int n = n0 + wc * 64 + j * 16 + lr;
      float bv = bias[n];
      int which = n >> 10, cc = n & 1023, h = cc >> 6, d = cc & 63;
      #pragma unroll
      for (int r = 0; r < 4; ++r) {
        int m = m0 + wr * 64 + i * 16 + lh * 4 + r;
        int bb = m >> 11, t = m & 2047;
        unsigned short val = f2b(acc[i][j][r] + bv);
        if (which == 0)
          Qb[((size_t)(bb * 16 + h) * SEQ + t) * HD + d] = val;
        else if (which == 1)
          Kb[((size_t)(bb * 16 + h) * SEQ + t) * HD + d] = val;
        else
          Vt[((size_t)(bb * 16 + h) * HD + d) * SEQ + t] = val;
      }
    }
  }
}

// ---------------- flash attention (causal) ----------------
// Q,K: [BH][T][D] bf16, Vt: [BH][D][T] bf16 -> AO [B*T][C] bf16
// block = 256 threads (4 waves), each block: one (b,h), 64 q rows; wave: 16 q rows.

__global__ __launch_bounds__(256) void attn_fwd(
    const unsigned short* __restrict__ Qb,
    const unsigned short* __restrict__ Kb,
    const unsigned short* __restrict__ Vt,
    unsigned short* __restrict__ AO) {
  __shared__ __align__(16) unsigned short Ks[64 * 64];
  __shared__ __align__(16) unsigned short Vs[64 * 64];   // [d][kv]
  __shared__ __align__(16) unsigned short Ps[4][16 * 64];

  int tid = threadIdx.x;
  int lane = tid & 63, w = tid >> 6;
  int lr = lane & 15, lh = lane >> 4;
  int wbase = tid & 192;
  int bid = blockIdx.x;
  int qt = bid & 31, bh = bid >> 5;
  int b = bh >> 4, h = bh & 15;
  int q0 = qt * 64;

  const unsigned short* Qh = Qb + (size_t)bh * SEQ * HD;
  const unsigned short* Kh = Kb + (size_t)bh * SEQ * HD;
  const unsigned short* Vh = Vt + (size_t)bh * HD * SEQ;

  // Q fragments (16 rows per wave, D=64 -> two K=32 halves)
  int qrow = q0 + w * 16 + lr;
  bf16x8 qf[2];
  qf[0] = *reinterpret_cast<const bf16x8*>(&Qh[(size_t)qrow * HD + lh * 8]);
  qf[1] = *reinterpret_cast<const bf16x8*>(&Qh[(size_t)qrow * HD + 32 + lh * 8]);

  f32x4 o[4];
  #pragma unroll
  for (int dg = 0; dg < 4; ++dg) o[dg] = f32x4{0.f, 0.f, 0.f, 0.f};
  float mrun[4], lrun[4];
  #pragma unroll
  for (int r = 0; r < 4; ++r) { mrun[r] = -1e30f; lrun[r] = 0.f; }

  for (int kv0 = 0; kv0 <= q0; kv0 += 64) {
    // stage K [kv][d] and V^T [d][kv]
    #pragma unroll
    for (int c = 0; c < 2; ++c) {
      int idx = c * 256 + tid;
      int row = idx >> 3, col = (idx & 7) * 8;
      const unsigned short* srcK = Kh + (size_t)(kv0 + row) * HD + col;
      __builtin_amdgcn_global_load_lds((const __attribute__((address_space(1))) void*)srcK,
          (__attribute__((address_space(3))) void*)&Ks[(c * 256 + wbase) * 8], 16, 0, 0);
      const unsigned short* srcV = Vh + (size_t)row * SEQ + kv0 + col;
      __builtin_amdgcn_global_load_lds((const __attribute__((address_space(1))) void*)srcV,
          (__attribute__((address_space(3))) void*)&Vs[(c * 256 + wbase) * 8], 16, 0, 0);
    }
    __syncthreads();

    // S = Q K^T  (16 q rows x 64 kv cols per wave)
    f32x4 s[4];
    #pragma unroll
    for (int g = 0; g < 4; ++g) s[g] = f32x4{0.f, 0.f, 0.f, 0.f};
    #pragma unroll
    for (int g = 0; g < 4; ++g) {
      #pragma unroll
      for (int kh = 0; kh < 2; ++kh) {
        bf16x8 kf = *reinterpret_cast<const bf16x8*>(&Ks[(g * 16 + lr) * 64 + kh * 32 + lh * 8]);
        s[g] = __builtin_amdgcn_mfma_f32_16x16x32_bf16(qf[kh], kf, s[g], 0, 0, 0);
      }
    }

    bool diag = (kv0 == q0);
    float sv[4][4];
    #pragma unroll
    for (int g = 0; g < 4; ++g)
      #pragma unroll
      for (int r = 0; r < 4; ++r) {
        float v = s[g][r] * 0.125f;  // 1/sqrt(64)
        if (diag && (g * 16 + lr) > (w * 16 + lh * 4 + r)) v = -1e30f;
        sv[g][r] = v;
      }

    // row max over 64 kv: local over g, then over the 16 lanes sharing lh
    float rm[4];
    #pragma unroll
    for (int r = 0; r < 4; ++r)
      rm[r] = fmaxf(fmaxf(sv[0][r], sv[1][r]), fmaxf(sv[2][r], sv[3][r]));
    #pragma unroll
    for (int d = 1; d < 16; d <<= 1)
      #pragma unroll
      for (int r = 0; r < 4; ++r)
        rm[r] = fmaxf(rm[r], __shfl_xor(rm[r], d));

    float alpha[4];
    #pragma unroll
    for (int r = 0; r < 4; ++r) {
      float mnew = fmaxf(mrun[r], rm[r]);
      alpha[r] = __expf(mrun[r] - mnew);
      mrun[r] = mnew;
    }

    float rs[4] = {0.f, 0.f, 0.f, 0.f};
    #pragma unroll
    for (int g = 0; g < 4; ++g)
      #pragma unroll
      for (int r = 0; r < 4; ++r) {
        float p = __expf(sv[g][r] - mrun[r]);
        sv[g][r] = p;
        rs[r] += p;
      }
    #pragma unroll
    for (int d = 1; d < 16; d <<= 1)
      #pragma unroll
      for (int r = 0; r < 4; ++r)
        rs[r] += __shfl_xor(rs[r], d);
    #pragma unroll
    for (int r = 0; r < 4; ++r)
      lrun[r] = lrun[r] * alpha[r] + rs[r];

    #pragma unroll
    for (int dg = 0; dg < 4; ++dg)
      #pragma unroll
      for (int r = 0; r < 4; ++r)
        o[dg][r] *= alpha[r];

    // bounce P through LDS: C/D layout -> A-frag layout
    #pragma unroll
    for (int g = 0; g < 4; ++g)
      #pragma unroll
      for (int r = 0; r < 4; ++r)
        Ps[w][(lh * 4 + r) * 64 + g * 16 + lr] = f2b(sv[g][r]);

    bf16x8 pa[2];
    pa[0] = *reinterpret_cast<const bf16x8*>(&Ps[w][lr * 64 + lh * 8]);
    pa[1] = *reinterpret_cast<const bf16x8*>(&Ps[w][lr * 64 + 32 + lh * 8]);

    #pragma unroll
    for (int dg = 0; dg < 4; ++dg) {
      #pragma unroll
      for (int kh = 0; kh < 2; ++kh) {
        bf16x8 vf = *reinterpret_cast<const bf16x8*>(&Vs[(dg * 16 + lr) * 64 + kh * 32 + lh * 8]);
        o[dg] = __builtin_amdgcn_mfma_f32_16x16x32_bf16(pa[kh], vf, o[dg], 0, 0, 0);
      }
    }
    __syncthreads();
  }

  // normalize and store to AO [B*T][C]
  #pragma unroll
  for (int r = 0; r < 4; ++r) {
    float inv = 1.0f / lrun[r];
    size_t row = (size_t)(b * SEQ + q0 + w * 16 + lh * 4 + r) * CH;
    #pragma unroll
    for (int dg = 0; dg < 4; ++dg)
      AO[row + h * 64 + dg * 16 + lr] = f2b(o[dg][r] * inv);
  }
}

// ---------------- GEMM2: out = AO @ w_proj + b (fp32 out) ----------------

__global__ __launch_bounds__(256) void gemm_proj(
    const unsigned short* __restrict__ A,   // [8192][1024]
    const unsigned short* __restrict__ Bt,  // [1024][1024]
    const float* __restrict__ bias,
    float* __restrict__ out) {
  constexpr int K = 1024;
  __shared__ __align__(16) unsigned short As[128 * 32];
  __shared__ __align__(16) unsigned short Bs[128 * 32];
  int tid = threadIdx.x;
  int lane = tid & 63, wav = tid >> 6;
  int wr = wav >> 1, wc = wav & 1;
  int lr = lane & 15, lh = lane >> 4;
  int wbase = tid & 192;
  int m0 = blockIdx.x * 128, n0 = blockIdx.y * 128;

  f32x4 acc[4][4];
  #pragma unroll
  for (int i = 0; i < 4; ++i)
    #pragma unroll
    for (int j = 0; j < 4; ++j)
      acc[i][j] = f32x4{0.f, 0.f, 0.f, 0.f};

  for (int k0 = 0; k0 < K; k0 += 32) {
    #pragma unroll
    for (int c = 0; c < 2; ++c) {
      int idx = c * 256 + tid;
      const unsigned short* srcA = A + (size_t)(m0 + (idx >> 2)) * K + k0 + (idx & 3) * 8;
      __builtin_amdgcn_global_load_lds((const __attribute__((address_space(1))) void*)srcA,
          (__attribute__((address_space(3))) void*)&As[(c * 256 + wbase) * 8], 16, 0, 0);
      const unsigned short* srcB = Bt + (size_t)(n0 + (idx >> 2)) * K + k0 + (idx & 3) * 8;
      __builtin_amdgcn_global_load_lds((const __attribute__((address_space(1))) void*)srcB,
          (__attribute__((address_space(3))) void*)&Bs[(c * 256 + wbase) * 8], 16, 0, 0);
    }
    __syncthreads();
    bf16x8 a[4], b[4];
    #pragma unroll
    for (int i = 0; i < 4; ++i)
      a[i] = *reinterpret_cast<const bf16x8*>(&As[(wr * 64 + i * 16 + lr) * 32 + lh * 8]);
    #pragma unroll
    for (int j = 0; j < 4; ++j)
      b[j] = *reinterpret_cast<const bf16x8*>(&Bs[(wc * 64 + j * 16 + lr) * 32 + lh * 8]);
    #pragma unroll
    for (int i = 0; i < 4; ++i)
      #pragma unroll
      for (int j = 0; j < 4; ++j)
        acc[i][j] = __builtin_amdgcn_mfma_f32_16x16x32_bf16(a[i], b[j], acc[i][j], 0, 0, 0);
    __syncthreads();
  }

  #pragma unroll
  for (int i = 0; i < 4; ++i) {
    #pragma unroll
    for (int j = 0; j < 4; ++j) {
      int n = n0 + wc * 64 + j * 16 + lr;
      float bv = bias[n];
      #pragma unroll
      for (int r = 0; r < 4; ++r) {
        int m = m0 + wr * 64 + i * 16 + lh * 4 + r;
        out[(size_t)m * 1024 + n] = acc[i][j][r] + bv;
      }
    }
  }
}

// ---------------- launcher ----------------

extern "C" void kernel_launch(void* const* d_in, const int* in_sizes, int n_in,
                              void* d_out, int out_size, void* d_ws, size_t ws_size,
                              hipStream_t stream) {
  const float* x      = (const float*)d_in[0];
  const float* w_attn = (const float*)d_in[1];
  const float* b_attn = (const float*)d_in[2];
  const float* w_proj = (const float*)d_in[3];
  const float* b_proj = (const float*)d_in[4];
  float* out = (float*)d_out;

  char* ws = (char*)d_ws;
  // workspace layout (bytes)
  unsigned short* xb  = (unsigned short*)(ws);                       // 16 MB  [8192][1024]
  unsigned short* wAT = (unsigned short*)(ws + 16777216);            // 6 MB   [3072][1024]
  unsigned short* wPT = (unsigned short*)(ws + 23068672);            // 2 MB   [1024][1024]
  unsigned short* Qb  = (unsigned short*)(ws + 25165824);            // 16 MB  [64][2048][64]
  unsigned short* Kb  = (unsigned short*)(ws + 41943040);            // 16 MB
  unsigned short* Vt  = (unsigned short*)(ws + 58720256);            // 16 MB  [64][64][2048]
  unsigned short* AO  = (unsigned short*)(ws + 75497472);            // 16 MB  [8192][1024]

  // 1. convert x to bf16
  conv_x_bf16<<<(BT * CH / 4 + 255) / 256, 256, 0, stream>>>(x, xb, BT * CH / 4);
  // 2. transpose + convert weights
  transpose_w_bf16<<<dim3(3 * CH / 32, CH / 32), dim3(32, 8), 0, stream>>>(w_attn, wAT, CH, 3 * CH);
  transpose_w_bf16<<<dim3(CH / 32, CH / 32), dim3(32, 8), 0, stream>>>(w_proj, wPT, CH, CH);
  // 3. QKV gemm + scatter
  gemm_qkv<<<dim3(BT / 128, 3 * CH / 128), 256, 0, stream>>>(xb, wAT, b_attn, Qb, Kb, Vt);
  // 4. flash attention
  attn_fwd<<<BATCH * NH * (SEQ / 64), 256, 0, stream>>>(Qb, Kb, Vt, AO);
  // 5. projection
  gemm_proj<<<dim3(BT / 128, CH / 128), 256, 0, stream>>>(AO, wPT, b_proj, out);
}

// Round 2
// 339.344 us; speedup vs baseline: 1.1662x; 1.1662x over previous
//
#include <hip/hip_runtime.h>
#include <hip/hip_bf16.h>

// Problem constants: B=4, T=2048, C=1024, H=16, D=64
#define BATCH 4
#define SEQ   2048
#define CH    1024
#define NH    16
#define HD    64
#define BT    8192   // BATCH*SEQ

typedef __attribute__((ext_vector_type(8))) short bf16x8;
typedef __attribute__((ext_vector_type(4))) float f32x4;

__device__ __forceinline__ unsigned short f2b(float f) {
  __hip_bfloat16 h = __float2bfloat16(f);
  return *reinterpret_cast<unsigned short*>(&h);
}

// ---------------- conversion kernels ----------------

__global__ void conv_x_bf16(const float* __restrict__ in, unsigned short* __restrict__ out, int n4) {
  int i = blockIdx.x * blockDim.x + threadIdx.x;
  if (i >= n4) return;
  float4 v = reinterpret_cast<const float4*>(in)[i];
  ushort4 o;
  o.x = f2b(v.x); o.y = f2b(v.y); o.z = f2b(v.z); o.w = f2b(v.w);
  reinterpret_cast<ushort4*>(out)[i] = o;
}

// in[R][Cc] f32  ->  out[Cc][R] bf16
__global__ void transpose_w_bf16(const float* __restrict__ in, unsigned short* __restrict__ out,
                                 int R, int Cc) {
  __shared__ float tile[32][33];
  int c0 = blockIdx.x * 32, r0 = blockIdx.y * 32;
  int tx = threadIdx.x, ty = threadIdx.y;
  #pragma unroll
  for (int i = 0; i < 32; i += 8)
    tile[ty + i][tx] = in[(size_t)(r0 + ty + i) * Cc + c0 + tx];
  __syncthreads();
  #pragma unroll
  for (int i = 0; i < 32; i += 8)
    out[(size_t)(c0 + ty + i) * R + r0 + tx] = f2b(tile[tx][ty + i]);
}

// ---------------- GEMM1: qkv = x @ w_attn + b, scatter to Q/K/Vt ----------------
// A  [8192][1024] bf16, BT(w_attn^T) [3072][1024] bf16
// Q (pre-scaled by 1/sqrt(D)*log2e), K: [B*H][T][D] bf16 ; Vt: [B*H][D][T] bf16

#define QSCALE 0.18033688011112042f   // 0.125 * log2(e)

__global__ __launch_bounds__(256) void gemm_qkv(
    const unsigned short* __restrict__ A,
    const unsigned short* __restrict__ Bt,
    const float* __restrict__ bias,
    unsigned short* __restrict__ Qb,
    unsigned short* __restrict__ Kb,
    unsigned short* __restrict__ Vt) {
  constexpr int K = 1024;
  __shared__ __align__(16) unsigned short As[128 * 32];
  __shared__ __align__(16) unsigned short Bs[128 * 32];
  int tid = threadIdx.x;
  int lane = tid & 63, wav = tid >> 6;
  int wr = wav >> 1, wc = wav & 1;
  int lr = lane & 15, lh = lane >> 4;
  int wbase = tid & 192;
  int m0 = blockIdx.x * 128, n0 = blockIdx.y * 128;

  f32x4 acc[4][4];
  #pragma unroll
  for (int i = 0; i < 4; ++i)
    #pragma unroll
    for (int j = 0; j < 4; ++j)
      acc[i][j] = f32x4{0.f, 0.f, 0.f, 0.f};

  for (int k0 = 0; k0 < K; k0 += 32) {
    #pragma unroll
    for (int c = 0; c < 2; ++c) {
      int idx = c * 256 + tid;
      const unsigned short* srcA = A + (size_t)(m0 + (idx >> 2)) * K + k0 + (idx & 3) * 8;
      __builtin_amdgcn_global_load_lds((const __attribute__((address_space(1))) void*)srcA,
          (__attribute__((address_space(3))) void*)&As[(c * 256 + wbase) * 8], 16, 0, 0);
      const unsigned short* srcB = Bt + (size_t)(n0 + (idx >> 2)) * K + k0 + (idx & 3) * 8;
      __builtin_amdgcn_global_load_lds((const __attribute__((address_space(1))) void*)srcB,
          (__attribute__((address_space(3))) void*)&Bs[(c * 256 + wbase) * 8], 16, 0, 0);
    }
    __syncthreads();
    bf16x8 a[4], b[4];
    #pragma unroll
    for (int i = 0; i < 4; ++i)
      a[i] = *reinterpret_cast<const bf16x8*>(&As[(wr * 64 + i * 16 + lr) * 32 + lh * 8]);
    #pragma unroll
    for (int j = 0; j < 4; ++j)
      b[j] = *reinterpret_cast<const bf16x8*>(&Bs[(wc * 64 + j * 16 + lr) * 32 + lh * 8]);
    #pragma unroll
    for (int i = 0; i < 4; ++i)
      #pragma unroll
      for (int j = 0; j < 4; ++j)
        acc[i][j] = __builtin_amdgcn_mfma_f32_16x16x32_bf16(a[i], b[j], acc[i][j], 0, 0, 0);
    __syncthreads();
  }

  #pragma unroll
  for (int i = 0; i < 4; ++i) {
    #pragma unroll
    for (int j = 0; j < 4; ++j) {
      int n = n0 + wc * 64 + j * 16 + lr;
      float bv = bias[n];
      int which = n >> 10, cc = n & 1023, h = cc >> 6, d = cc & 63;
      #pragma unroll
      for (int r = 0; r < 4; ++r) {
        int m = m0 + wr * 64 + i * 16 + lh * 4 + r;
        int bb = m >> 11, t = m & 2047;
        float v = acc[i][j][r] + bv;
        if (which == 0)
          Qb[((size_t)(bb * 16 + h) * SEQ + t) * HD + d] = f2b(v * QSCALE);
        else if (which == 1)
          Kb[((size_t)(bb * 16 + h) * SEQ + t) * HD + d] = f2b(v);
        else
          Vt[((size_t)(bb * 16 + h) * HD + d) * SEQ + t] = f2b(v);
      }
    }
  }
}

// ---------------- flash attention (causal) ----------------
// Q (pre-scaled),K: [BH][T][D] bf16, Vt: [BH][D][T] bf16 -> AO [B*T][C] bf16
// block = 256 threads (4 waves), each block: one (b,h), 64 q rows; wave: 16 q rows.
// K/V double-buffered in LDS, XOR-swizzled (chunk ^= row&7) via pre-swizzled
// global source (rule #21). Ps swizzled both sides. One barrier per kv tile.

__global__ __launch_bounds__(256) void attn_fwd(
    const unsigned short* __restrict__ Qb,
    const unsigned short* __restrict__ Kb,
    const unsigned short* __restrict__ Vt,
    unsigned short* __restrict__ AO) {
  __shared__ __align__(16) unsigned short Ks[2][64 * 64];
  __shared__ __align__(16) unsigned short Vs[2][64 * 64];   // [d][kv]
  __shared__ __align__(16) unsigned short Ps[4][16 * 64];

  int tid = threadIdx.x;
  int lane = tid & 63, w = tid >> 6;
  int lr = lane & 15, lh = lane >> 4;
  int wbase = tid & 192;
  int bid = blockIdx.x;
  int qt = 31 - (bid & 31), bh = bid >> 5;   // reversed: heavy q-tiles first
  int b = bh >> 4, h = bh & 15;
  int q0 = qt * 64;

  const unsigned short* Qh = Qb + (size_t)bh * SEQ * HD;
  const unsigned short* Kh = Kb + (size_t)bh * SEQ * HD;
  const unsigned short* Vh = Vt + (size_t)bh * HD * SEQ;

// stage one 64x64 K tile + 64x64 V^T tile into buffer BUF with source-side
// chunk swizzle: LDS stays linear, global chunk cg = c ^ (row&7).
#define STAGE_KV(BUF, KV0)                                                                  \
  {                                                                                         \
    _Pragma("unroll")                                                                       \
    for (int c = 0; c < 2; ++c) {                                                           \
      int idx = c * 256 + tid;                                                              \
      int row = idx >> 3;                                                                   \
      int cg = (idx & 7) ^ (row & 7);                                                       \
      const unsigned short* srcK = Kh + (size_t)((KV0) + row) * HD + cg * 8;                \
      __builtin_amdgcn_global_load_lds((const __attribute__((address_space(1))) void*)srcK, \
          (__attribute__((address_space(3))) void*)&Ks[BUF][(c * 256 + wbase) * 8], 16, 0, 0); \
      const unsigned short* srcV = Vh + (size_t)row * SEQ + (KV0) + cg * 8;                 \
      __builtin_amdgcn_global_load_lds((const __attribute__((address_space(1))) void*)srcV, \
          (__attribute__((address_space(3))) void*)&Vs[BUF][(c * 256 + wbase) * 8], 16, 0, 0); \
    }                                                                                       \
  }

  // Q fragments (16 rows per wave, D=64 -> two K=32 halves); Q is pre-scaled
  int qrow = q0 + w * 16 + lr;
  bf16x8 qf[2];
  qf[0] = *reinterpret_cast<const bf16x8*>(&Qh[(size_t)qrow * HD + lh * 8]);
  qf[1] = *reinterpret_cast<const bf16x8*>(&Qh[(size_t)qrow * HD + 32 + lh * 8]);

  f32x4 o[4];
  #pragma unroll
  for (int dg = 0; dg < 4; ++dg) o[dg] = f32x4{0.f, 0.f, 0.f, 0.f};
  float mrun[4], lrun[4];
  #pragma unroll
  for (int r = 0; r < 4; ++r) { mrun[r] = -1e30f; lrun[r] = 0.f; }

  // prologue: stage tile 0
  STAGE_KV(0, 0)
  asm volatile("s_waitcnt vmcnt(0)" ::: "memory");
  __builtin_amdgcn_s_barrier();

  int cur = 0;
  for (int kv0 = 0; kv0 <= q0; kv0 += 64) {
    // issue next tile's staging (overlaps with this tile's compute)
    if (kv0 + 64 <= q0) STAGE_KV(cur ^ 1, kv0 + 64)

    // S = Q K^T  (16 q rows x 64 kv cols per wave)
    f32x4 s[4];
    #pragma unroll
    for (int g = 0; g < 4; ++g) s[g] = f32x4{0.f, 0.f, 0.f, 0.f};
    #pragma unroll
    for (int g = 0; g < 4; ++g) {
      #pragma unroll
      for (int kh = 0; kh < 2; ++kh) {
        bf16x8 kf = *reinterpret_cast<const bf16x8*>(
            &Ks[cur][(g * 16 + lr) * 64 + (((kh * 4 + lh) ^ (lr & 7)) << 3)]);
        s[g] = __builtin_amdgcn_mfma_f32_16x16x32_bf16(qf[kh], kf, s[g], 0, 0, 0);
      }
    }

    bool diag = (kv0 == q0);
    float sv[4][4];
    #pragma unroll
    for (int g = 0; g < 4; ++g)
      #pragma unroll
      for (int r = 0; r < 4; ++r) {
        float v = s[g][r];   // scale pre-folded into Q (incl. log2e)
        if (diag && (g * 16 + lr) > (w * 16 + lh * 4 + r)) v = -1e30f;
        sv[g][r] = v;
      }

    // row max over 64 kv: local over g, then over the 16 lanes sharing lh
    float rm[4];
    #pragma unroll
    for (int r = 0; r < 4; ++r)
      rm[r] = fmaxf(fmaxf(sv[0][r], sv[1][r]), fmaxf(sv[2][r], sv[3][r]));
    #pragma unroll
    for (int d = 1; d < 16; d <<= 1)
      #pragma unroll
      for (int r = 0; r < 4; ++r)
        rm[r] = fmaxf(rm[r], __shfl_xor(rm[r], d));

    float alpha[4];
    #pragma unroll
    for (int r = 0; r < 4; ++r) {
      float mnew = fmaxf(mrun[r], rm[r]);
      alpha[r] = exp2f(mrun[r] - mnew);
      mrun[r] = mnew;
    }

    float rs[4] = {0.f, 0.f, 0.f, 0.f};
    #pragma unroll
    for (int g = 0; g < 4; ++g)
      #pragma unroll
      for (int r = 0; r < 4; ++r) {
        float p = exp2f(sv[g][r] - mrun[r]);
        sv[g][r] = p;
        rs[r] += p;
      }
    #pragma unroll
    for (int d = 1; d < 16; d <<= 1)
      #pragma unroll
      for (int r = 0; r < 4; ++r)
        rs[r] += __shfl_xor(rs[r], d);
    #pragma unroll
    for (int r = 0; r < 4; ++r)
      lrun[r] = lrun[r] * alpha[r] + rs[r];

    #pragma unroll
    for (int dg = 0; dg < 4; ++dg)
      #pragma unroll
      for (int r = 0; r < 4; ++r)
        o[dg][r] *= alpha[r];

    // bounce P through LDS: C/D layout -> A-frag layout (swizzled both sides)
    #pragma unroll
    for (int g = 0; g < 4; ++g)
      #pragma unroll
      for (int r = 0; r < 4; ++r) {
        int prow = lh * 4 + r;
        int pcol = (g * 16 + lr) ^ ((prow & 7) << 3);
        Ps[w][prow * 64 + pcol] = f2b(sv[g][r]);
      }

    bf16x8 pa[2];
    pa[0] = *reinterpret_cast<const bf16x8*>(&Ps[w][lr * 64 + ((lh ^ (lr & 7)) << 3)]);
    pa[1] = *reinterpret_cast<const bf16x8*>(&Ps[w][lr * 64 + (((4 + lh) ^ (lr & 7)) << 3)]);

    #pragma unroll
    for (int dg = 0; dg < 4; ++dg) {
      #pragma unroll
      for (int kh = 0; kh < 2; ++kh) {
        bf16x8 vf = *reinterpret_cast<const bf16x8*>(
            &Vs[cur][(dg * 16 + lr) * 64 + (((kh * 4 + lh) ^ (lr & 7)) << 3)]);
        o[dg] = __builtin_amdgcn_mfma_f32_16x16x32_bf16(pa[kh], vf, o[dg], 0, 0, 0);
      }
    }

    // drain next-tile staging, then barrier: one barrier per tile
    asm volatile("s_waitcnt vmcnt(0)" ::: "memory");
    __builtin_amdgcn_s_barrier();
    cur ^= 1;
  }

  // normalize and store to AO [B*T][C]
  #pragma unroll
  for (int r = 0; r < 4; ++r) {
    float inv = 1.0f / lrun[r];
    size_t row = (size_t)(b * SEQ + q0 + w * 16 + lh * 4 + r) * CH;
    #pragma unroll
    for (int dg = 0; dg < 4; ++dg)
      AO[row + h * 64 + dg * 16 + lr] = f2b(o[dg][r] * inv);
  }
}

// ---------------- GEMM2: out = AO @ w_proj + b (fp32 out) ----------------

__global__ __launch_bounds__(256) void gemm_proj(
    const unsigned short* __restrict__ A,   // [8192][1024]
    const unsigned short* __restrict__ Bt,  // [1024][1024]
    const float* __restrict__ bias,
    float* __restrict__ out) {
  constexpr int K = 1024;
  __shared__ __align__(16) unsigned short As[128 * 32];
  __shared__ __align__(16) unsigned short Bs[128 * 32];
  int tid = threadIdx.x;
  int lane = tid & 63, wav = tid >> 6;
  int wr = wav >> 1, wc = wav & 1;
  int lr = lane & 15, lh = lane >> 4;
  int wbase = tid & 192;
  int m0 = blockIdx.x * 128, n0 = blockIdx.y * 128;

  f32x4 acc[4][4];
  #pragma unroll
  for (int i = 0; i < 4; ++i)
    #pragma unroll
    for (int j = 0; j < 4; ++j)
      acc[i][j] = f32x4{0.f, 0.f, 0.f, 0.f};

  for (int k0 = 0; k0 < K; k0 += 32) {
    #pragma unroll
    for (int c = 0; c < 2; ++c) {
      int idx = c * 256 + tid;
      const unsigned short* srcA = A + (size_t)(m0 + (idx >> 2)) * K + k0 + (idx & 3) * 8;
      __builtin_amdgcn_global_load_lds((const __attribute__((address_space(1))) void*)srcA,
          (__attribute__((address_space(3))) void*)&As[(c * 256 + wbase) * 8], 16, 0, 0);
      const unsigned short* srcB = Bt + (size_t)(n0 + (idx >> 2)) * K + k0 + (idx & 3) * 8;
      __builtin_amdgcn_global_load_lds((const __attribute__((address_space(1))) void*)srcB,
          (__attribute__((address_space(3))) void*)&Bs[(c * 256 + wbase) * 8], 16, 0, 0);
    }
    __syncthreads();
    bf16x8 a[4], b[4];
    #pragma unroll
    for (int i = 0; i < 4; ++i)
      a[i] = *reinterpret_cast<const bf16x8*>(&As[(wr * 64 + i * 16 + lr) * 32 + lh * 8]);
    #pragma unroll
    for (int j = 0; j < 4; ++j)
      b[j] = *reinterpret_cast<const bf16x8*>(&Bs[(wc * 64 + j * 16 + lr) * 32 + lh * 8]);
    #pragma unroll
    for (int i = 0; i < 4; ++i)
      #pragma unroll
      for (int j = 0; j < 4; ++j)
        acc[i][j] = __builtin_amdgcn_mfma_f32_16x16x32_bf16(a[i], b[j], acc[i][j], 0, 0, 0);
    __syncthreads();
  }

  #pragma unroll
  for (int i = 0; i < 4; ++i) {
    #pragma unroll
    for (int j = 0; j < 4; ++j) {
      int n = n0 + wc * 64 + j * 16 + lr;
      float bv = bias[n];
      #pragma unroll
      for (int r = 0; r < 4; ++r) {
        int m = m0 + wr * 64 + i * 16 + lh * 4 + r;
        out[(size_t)m * 1024 + n] = acc[i][j][r] + bv;
      }
    }
  }
}

// ---------------- launcher ----------------

extern "C" void kernel_launch(void* const* d_in, const int* in_sizes, int n_in,
                              void* d_out, int out_size, void* d_ws, size_t ws_size,
                              hipStream_t stream) {
  const float* x      = (const float*)d_in[0];
  const float* w_attn = (const float*)d_in[1];
  const float* b_attn = (const float*)d_in[2];
  const float* w_proj = (const float*)d_in[3];
  const float* b_proj = (const float*)d_in[4];
  float* out = (float*)d_out;

  char* ws = (char*)d_ws;
  unsigned short* xb  = (unsigned short*)(ws);                       // 16 MB  [8192][1024]
  unsigned short* wAT = (unsigned short*)(ws + 16777216);            // 6 MB   [3072][1024]
  unsigned short* wPT = (unsigned short*)(ws + 23068672);            // 2 MB   [1024][1024]
  unsigned short* Qb  = (unsigned short*)(ws + 25165824);            // 16 MB  [64][2048][64]
  unsigned short* Kb  = (unsigned short*)(ws + 41943040);            // 16 MB
  unsigned short* Vt  = (unsigned short*)(ws + 58720256);            // 16 MB  [64][64][2048]
  unsigned short* AO  = (unsigned short*)(ws + 75497472);            // 16 MB  [8192][1024]

  conv_x_bf16<<<(BT * CH / 4 + 255) / 256, 256, 0, stream>>>(x, xb, BT * CH / 4);
  transpose_w_bf16<<<dim3(3 * CH / 32, CH / 32), dim3(32, 8), 0, stream>>>(w_attn, wAT, CH, 3 * CH);
  transpose_w_bf16<<<dim3(CH / 32, CH / 32), dim3(32, 8), 0, stream>>>(w_proj, wPT, CH, CH);
  gemm_qkv<<<dim3(BT / 128, 3 * CH / 128), 256, 0, stream>>>(xb, wAT, b_attn, Qb, Kb, Vt);
  attn_fwd<<<BATCH * NH * (SEQ / 64), 256, 0, stream>>>(Qb, Kb, Vt, AO);
  gemm_proj<<<dim3(BT / 128, CH / 128), 256, 0, stream>>>(AO, wPT, b_proj, out);
}

// Round 3
// 185.508 us; speedup vs baseline: 2.1333x; 1.8293x over previous
//
#include <hip/hip_runtime.h>
#include <hip/hip_bf16.h>

// Problem constants: B=4, T=2048, C=1024, H=16, D=64
#define BATCH 4
#define SEQ   2048
#define CH    1024
#define NH    16
#define HD    64
#define BT    8192   // BATCH*SEQ

typedef __attribute__((ext_vector_type(8))) short bf16x8;
typedef __attribute__((ext_vector_type(4))) float f32x4;
typedef __attribute__((ext_vector_type(16))) float f32x16;

__device__ __forceinline__ unsigned short f2b(float f) {
  __hip_bfloat16 h = __float2bfloat16(f);
  return *reinterpret_cast<unsigned short*>(&h);
}

__device__ __forceinline__ unsigned cvt_pk(float lo, float hi_) {
  unsigned r;
  asm("v_cvt_pk_bf16_f32 %0, %1, %2" : "=v"(r) : "v"(lo), "v"(hi_));
  return r;
}
// swap: a' = [a_lo | b_lo], b' = [a_hi | b_hi]
__device__ __forceinline__ void plane_swap(unsigned &a, unsigned &b) {
  asm("v_permlane32_swap_b32 %0, %1" : "+v"(a), "+v"(b));
}

// ---------------- conversion kernels ----------------

__global__ void conv_x_bf16(const float* __restrict__ in, unsigned short* __restrict__ out, int n4) {
  int i = blockIdx.x * blockDim.x + threadIdx.x;
  if (i >= n4) return;
  float4 v = reinterpret_cast<const float4*>(in)[i];
  ushort4 o;
  o.x = f2b(v.x); o.y = f2b(v.y); o.z = f2b(v.z); o.w = f2b(v.w);
  reinterpret_cast<ushort4*>(out)[i] = o;
}

// in[R][Cc] f32  ->  out[Cc][R] bf16
__global__ void transpose_w_bf16(const float* __restrict__ in, unsigned short* __restrict__ out,
                                 int R, int Cc) {
  __shared__ float tile[32][33];
  int c0 = blockIdx.x * 32, r0 = blockIdx.y * 32;
  int tx = threadIdx.x, ty = threadIdx.y;
  #pragma unroll
  for (int i = 0; i < 32; i += 8)
    tile[ty + i][tx] = in[(size_t)(r0 + ty + i) * Cc + c0 + tx];
  __syncthreads();
  #pragma unroll
  for (int i = 0; i < 32; i += 8)
    out[(size_t)(c0 + ty + i) * R + r0 + tx] = f2b(tile[tx][ty + i]);
}

// ---------------- GEMM1: qkv = x @ w_attn + b, scatter to Q/K/Vt ----------------

#define QSCALE 0.18033688011112042f   // 0.125 * log2(e)

__global__ __launch_bounds__(256) void gemm_qkv(
    const unsigned short* __restrict__ A,
    const unsigned short* __restrict__ Bt,
    const float* __restrict__ bias,
    unsigned short* __restrict__ Qb,
    unsigned short* __restrict__ Kb,
    unsigned short* __restrict__ Vt) {
  constexpr int K = 1024;
  __shared__ __align__(16) unsigned short As[128 * 32];
  __shared__ __align__(16) unsigned short Bs[128 * 32];
  int tid = threadIdx.x;
  int lane = tid & 63, wav = tid >> 6;
  int wr = wav >> 1, wc = wav & 1;
  int lr = lane & 15, lh = lane >> 4;
  int wbase = tid & 192;
  int m0 = blockIdx.x * 128, n0 = blockIdx.y * 128;

  f32x4 acc[4][4];
  #pragma unroll
  for (int i = 0; i < 4; ++i)
    #pragma unroll
    for (int j = 0; j < 4; ++j)
      acc[i][j] = f32x4{0.f, 0.f, 0.f, 0.f};

  for (int k0 = 0; k0 < K; k0 += 32) {
    #pragma unroll
    for (int c = 0; c < 2; ++c) {
      int idx = c * 256 + tid;
      const unsigned short* srcA = A + (size_t)(m0 + (idx >> 2)) * K + k0 + (idx & 3) * 8;
      __builtin_amdgcn_global_load_lds((const __attribute__((address_space(1))) void*)srcA,
          (__attribute__((address_space(3))) void*)&As[(c * 256 + wbase) * 8], 16, 0, 0);
      const unsigned short* srcB = Bt + (size_t)(n0 + (idx >> 2)) * K + k0 + (idx & 3) * 8;
      __builtin_amdgcn_global_load_lds((const __attribute__((address_space(1))) void*)srcB,
          (__attribute__((address_space(3))) void*)&Bs[(c * 256 + wbase) * 8], 16, 0, 0);
    }
    __syncthreads();
    bf16x8 a[4], b[4];
    #pragma unroll
    for (int i = 0; i < 4; ++i)
      a[i] = *reinterpret_cast<const bf16x8*>(&As[(wr * 64 + i * 16 + lr) * 32 + lh * 8]);
    #pragma unroll
    for (int j = 0; j < 4; ++j)
      b[j] = *reinterpret_cast<const bf16x8*>(&Bs[(wc * 64 + j * 16 + lr) * 32 + lh * 8]);
    #pragma unroll
    for (int i = 0; i < 4; ++i)
      #pragma unroll
      for (int j = 0; j < 4; ++j)
        acc[i][j] = __builtin_amdgcn_mfma_f32_16x16x32_bf16(a[i], b[j], acc[i][j], 0, 0, 0);
    __syncthreads();
  }

  #pragma unroll
  for (int i = 0; i < 4; ++i) {
    #pragma unroll
    for (int j = 0; j < 4; ++j) {
      int n = n0 + wc * 64 + j * 16 + lr;
      float bv = bias[n];
      int which = n >> 10, cc = n & 1023, h = cc >> 6, d = cc & 63;
      #pragma unroll
      for (int r = 0; r < 4; ++r) {
        int m = m0 + wr * 64 + i * 16 + lh * 4 + r;
        int bb = m >> 11, t = m & 2047;
        float v = acc[i][j][r] + bv;
        if (which == 0)
          Qb[((size_t)(bb * 16 + h) * SEQ + t) * HD + d] = f2b(v * QSCALE);
        else if (which == 1)
          Kb[((size_t)(bb * 16 + h) * SEQ + t) * HD + d] = f2b(v);
        else
          Vt[((size_t)(bb * 16 + h) * HD + d) * SEQ + t] = f2b(v);
      }
    }
  }
}

// ---------------- flash attention (causal), 8-wave 32x32 swapped-operand ----------------
// Q (pre-scaled): [BH][T][D], K: [BH][T][D], Vt: [BH][D][T] -> AO [B*T][C] bf16
// Block: 512 threads (8 waves), 256 q rows (32/wave), KVBLK=64.
// S^T = mfma(K,Q) -> lane owns q=lane&31; in-register softmax; P->B-frag via
// cvt_pk + permlane32_swap (T12); O^T = mfma(V^T, P); LDS-bounce transpose at end.

__global__ __launch_bounds__(512, 2) void attn_fwd(
    const unsigned short* __restrict__ Qb,
    const unsigned short* __restrict__ Kb,
    const unsigned short* __restrict__ Vt,
    unsigned short* __restrict__ AO) {
  // sbuf shorts: [0,4096) K buf0 | [4096,8192) K buf1 | [8192,12288) V buf0 | [12288,16384) V buf1
  // end-of-kernel reuse: Ob[256][64] bf16 (all 16384)
  __shared__ __align__(16) unsigned short sbuf[16384];

  int tid = threadIdx.x;
  int lane = tid & 63, w = tid >> 6;
  int ql = lane & 31, hi = lane >> 5;
  int bid = blockIdx.x;
  int head = bid & 63;
  int qs = 7 - (bid >> 6);          // heavy q-slots dispatched first
  int q0 = qs * 256;
  int nt = 4 * (qs + 1);            // kv tiles of 64
  int b = head >> 4, h = head & 15;

  const unsigned short* Qh = Qb + (size_t)head * SEQ * HD;
  const unsigned short* Kh = Kb + (size_t)head * SEQ * HD;
  const unsigned short* Vh = Vt + (size_t)head * HD * SEQ;

// stage K tile [64][64] and V^T tile [64][64] with source-side chunk swizzle
#define STAGE(BUF, KV0)                                                                        \
  {                                                                                            \
    int row_ = tid >> 3;                                                                       \
    int cg_ = (tid & 7) ^ (row_ & 7);                                                          \
    const unsigned short* srcK_ = Kh + (size_t)((KV0) + row_) * HD + cg_ * 8;                  \
    __builtin_amdgcn_global_load_lds((const __attribute__((address_space(1))) void*)srcK_,     \
        (__attribute__((address_space(3))) void*)&sbuf[(BUF) * 4096 + (tid & ~63) * 8], 16, 0, 0); \
    const unsigned short* srcV_ = Vh + (size_t)row_ * SEQ + (KV0) + cg_ * 8;                   \
    __builtin_amdgcn_global_load_lds((const __attribute__((address_space(1))) void*)srcV_,     \
        (__attribute__((address_space(3))) void*)&sbuf[8192 + (BUF) * 4096 + (tid & ~63) * 8], 16, 0, 0); \
  }

  // Q as B-fragment: row=q=ql, k=d chunk (hi*8), per 16-d block
  int qg = q0 + w * 32 + ql;
  bf16x8 qf[4];
  #pragma unroll
  for (int dblk = 0; dblk < 4; ++dblk)
    qf[dblk] = *reinterpret_cast<const bf16x8*>(&Qh[(size_t)qg * HD + dblk * 16 + hi * 8]);

  f32x16 o0 = (f32x16)0.0f, o1 = (f32x16)0.0f;   // O^T: rows=d (2 blocks), col=q=ql
  float mrun = -1e30f, lrun = 0.f;

  STAGE(0, 0)
  asm volatile("s_waitcnt vmcnt(0)" ::: "memory");
  __builtin_amdgcn_s_barrier();

  int cur = 0;
  int wq_hi = q0 + w * 32 + 31;
  for (int t = 0; t < nt; ++t) {
    int kv0 = t * 64;
    if (t + 1 < nt) STAGE(cur ^ 1, kv0 + 64)

    if (kv0 <= wq_hi) {   // wave-uniform: this tile intersects my q range
      // ---- S^T = K·Q^T : C[kv][q], col=q=ql, rows=kv via (reg,hi) ----
      f32x16 s0 = (f32x16)0.0f, s1 = (f32x16)0.0f;
      int rk0 = ql, rk1 = 32 + ql;
      __builtin_amdgcn_s_setprio(1);
      #pragma unroll
      for (int dblk = 0; dblk < 4; ++dblk) {
        bf16x8 kf0 = *reinterpret_cast<const bf16x8*>(
            &sbuf[cur * 4096 + rk0 * 64 + (((dblk * 2 + hi) ^ (rk0 & 7)) << 3)]);
        s0 = __builtin_amdgcn_mfma_f32_32x32x16_bf16(kf0, qf[dblk], s0, 0, 0, 0);
        bf16x8 kf1 = *reinterpret_cast<const bf16x8*>(
            &sbuf[cur * 4096 + rk1 * 64 + (((dblk * 2 + hi) ^ (rk1 & 7)) << 3)]);
        s1 = __builtin_amdgcn_mfma_f32_32x32x16_bf16(kf1, qf[dblk], s1, 0, 0, 0);
      }
      __builtin_amdgcn_s_setprio(0);

      // ---- mask + gather into p[32] (kv = kv0 + 32*blk + cr + 4*hi) ----
      float p[32];
      bool needMask = (kv0 + 63 > q0 + 32 * w);
      #pragma unroll
      for (int r = 0; r < 16; ++r) {
        int cr = (r & 3) + 8 * (r >> 2);
        float v0 = s0[r], v1 = s1[r];
        if (needMask) {
          int kv_ = kv0 + 4 * hi + cr;
          v0 = (kv_ > qg) ? -1e30f : v0;
          v1 = (kv_ + 32 > qg) ? -1e30f : v1;
        }
        p[r] = v0; p[16 + r] = v1;
      }

      // ---- row max: in-register tree + one cross-half shfl ----
      float m16[16], m8[8], m4[4], m2[2];
      #pragma unroll
      for (int i = 0; i < 16; ++i) m16[i] = fmaxf(p[i], p[i + 16]);
      #pragma unroll
      for (int i = 0; i < 8; ++i) m8[i] = fmaxf(m16[i], m16[i + 8]);
      #pragma unroll
      for (int i = 0; i < 4; ++i) m4[i] = fmaxf(m8[i], m8[i + 4]);
      m2[0] = fmaxf(m4[0], m4[2]); m2[1] = fmaxf(m4[1], m4[3]);
      float mt = fmaxf(m2[0], m2[1]);
      mt = fmaxf(mt, __shfl_xor(mt, 32));
      float mnew = fmaxf(mrun, mt);
      float alpha = __builtin_amdgcn_exp2f(mrun - mnew);
      mrun = mnew;

      // ---- p = exp2(s - m), row sum ----
      #pragma unroll
      for (int i = 0; i < 32; ++i) p[i] = __builtin_amdgcn_exp2f(p[i] - mnew);
      float a16[16], a8[8], a4[4];
      #pragma unroll
      for (int i = 0; i < 16; ++i) a16[i] = p[i] + p[i + 16];
      #pragma unroll
      for (int i = 0; i < 8; ++i) a8[i] = a16[i] + a16[i + 8];
      #pragma unroll
      for (int i = 0; i < 4; ++i) a4[i] = a8[i] + a8[i + 4];
      float rs = (a4[0] + a4[1]) + (a4[2] + a4[3]);
      rs += __shfl_xor(rs, 32);
      lrun = lrun * alpha + rs;

      #pragma unroll
      for (int i = 0; i < 16; ++i) { o0[i] *= alpha; o1[i] *= alpha; }

      // ---- P -> B-fragments: 16 cvt_pk + 8 permlane32_swap (T12) ----
      union FU { unsigned u[4]; bf16x8 v; };
      FU fr[4];
      #pragma unroll
      for (int blk = 0; blk < 2; ++blk) {
        unsigned X = cvt_pk(p[blk * 16 + 0], p[blk * 16 + 1]);
        unsigned Z = cvt_pk(p[blk * 16 + 4], p[blk * 16 + 5]);
        plane_swap(X, Z);
        unsigned Y = cvt_pk(p[blk * 16 + 2], p[blk * 16 + 3]);
        unsigned W = cvt_pk(p[blk * 16 + 6], p[blk * 16 + 7]);
        plane_swap(Y, W);
        fr[blk * 2].u[0] = X; fr[blk * 2].u[1] = Y; fr[blk * 2].u[2] = Z; fr[blk * 2].u[3] = W;
        unsigned X2 = cvt_pk(p[blk * 16 + 8], p[blk * 16 + 9]);
        unsigned Z2 = cvt_pk(p[blk * 16 + 12], p[blk * 16 + 13]);
        plane_swap(X2, Z2);
        unsigned Y2 = cvt_pk(p[blk * 16 + 10], p[blk * 16 + 11]);
        unsigned W2 = cvt_pk(p[blk * 16 + 14], p[blk * 16 + 15]);
        plane_swap(Y2, W2);
        fr[blk * 2 + 1].u[0] = X2; fr[blk * 2 + 1].u[1] = Y2;
        fr[blk * 2 + 1].u[2] = Z2; fr[blk * 2 + 1].u[3] = W2;
      }

      // ---- O^T += V^T · P : C[d][q] ----
      __builtin_amdgcn_s_setprio(1);
      #pragma unroll
      for (int kc = 0; kc < 4; ++kc) {
        int rd0 = ql, rd1 = 32 + ql;
        bf16x8 vf0 = *reinterpret_cast<const bf16x8*>(
            &sbuf[8192 + cur * 4096 + rd0 * 64 + ((((kc << 1) + hi) ^ (rd0 & 7)) << 3)]);
        o0 = __builtin_amdgcn_mfma_f32_32x32x16_bf16(vf0, fr[kc].v, o0, 0, 0, 0);
        bf16x8 vf1 = *reinterpret_cast<const bf16x8*>(
            &sbuf[8192 + cur * 4096 + rd1 * 64 + ((((kc << 1) + hi) ^ (rd1 & 7)) << 3)]);
        o1 = __builtin_amdgcn_mfma_f32_32x32x16_bf16(vf1, fr[kc].v, o1, 0, 0, 0);
      }
      __builtin_amdgcn_s_setprio(0);
    }

    asm volatile("s_waitcnt vmcnt(0)" ::: "memory");
    __builtin_amdgcn_s_barrier();
    cur ^= 1;
  }

  // ---- epilogue: normalize, LDS-bounce transpose, coalesced store ----
  float inv = 1.0f / lrun;
  int qloc = w * 32 + ql;   // q within block
  #pragma unroll
  for (int dblk = 0; dblk < 2; ++dblk) {
    #pragma unroll
    for (int m = 0; m < 4; ++m) {
      // 4 consecutive d: d = dblk*32 + m*8 + 4*hi + {0..3}
      float v0, v1, v2, v3;
      if (dblk == 0) {
        v0 = o0[m * 4 + 0] * inv; v1 = o0[m * 4 + 1] * inv;
        v2 = o0[m * 4 + 2] * inv; v3 = o0[m * 4 + 3] * inv;
      } else {
        v0 = o1[m * 4 + 0] * inv; v1 = o1[m * 4 + 1] * inv;
        v2 = o1[m * 4 + 2] * inv; v3 = o1[m * 4 + 3] * inv;
      }
      unsigned u0 = (unsigned)f2b(v0) | ((unsigned)f2b(v1) << 16);
      unsigned u1 = (unsigned)f2b(v2) | ((unsigned)f2b(v3) << 16);
      int slot = (dblk * 4 + m) ^ (qloc & 7);
      unsigned long long val = (unsigned long long)u0 | ((unsigned long long)u1 << 32);
      *reinterpret_cast<unsigned long long*>(&sbuf[qloc * 64 + slot * 8 + hi * 4]) = val;
    }
  }
  __syncthreads();

  // store: 4 rounds, 8 threads per q row, 16B per thread, coalesced
  #pragma unroll
  for (int it = 0; it < 4; ++it) {
    int qr = it * 64 + (tid >> 3);
    int lc = tid & 7;
    int slot = lc ^ (qr & 7);
    bf16x8 v = *reinterpret_cast<const bf16x8*>(&sbuf[qr * 64 + slot * 8]);
    *reinterpret_cast<bf16x8*>(
        &AO[(size_t)(b * SEQ + q0 + qr) * CH + h * 64 + lc * 8]) = v;
  }
}

// ---------------- GEMM2: out = AO @ w_proj + b (fp32 out) ----------------

__global__ __launch_bounds__(256) void gemm_proj(
    const unsigned short* __restrict__ A,   // [8192][1024]
    const unsigned short* __restrict__ Bt,  // [1024][1024]
    const float* __restrict__ bias,
    float* __restrict__ out) {
  constexpr int K = 1024;
  __shared__ __align__(16) unsigned short As[128 * 32];
  __shared__ __align__(16) unsigned short Bs[128 * 32];
  int tid = threadIdx.x;
  int lane = tid & 63, wav = tid >> 6;
  int wr = wav >> 1, wc = wav & 1;
  int lr = lane & 15, lh = lane >> 4;
  int wbase = tid & 192;
  int m0 = blockIdx.x * 128, n0 = blockIdx.y * 128;

  f32x4 acc[4][4];
  #pragma unroll
  for (int i = 0; i < 4; ++i)
    #pragma unroll
    for (int j = 0; j < 4; ++j)
      acc[i][j] = f32x4{0.f, 0.f, 0.f, 0.f};

  for (int k0 = 0; k0 < K; k0 += 32) {
    #pragma unroll
    for (int c = 0; c < 2; ++c) {
      int idx = c * 256 + tid;
      const unsigned short* srcA = A + (size_t)(m0 + (idx >> 2)) * K + k0 + (idx & 3) * 8;
      __builtin_amdgcn_global_load_lds((const __attribute__((address_space(1))) void*)srcA,
          (__attribute__((address_space(3))) void*)&As[(c * 256 + wbase) * 8], 16, 0, 0);
      const unsigned short* srcB = Bt + (size_t)(n0 + (idx >> 2)) * K + k0 + (idx & 3) * 8;
      __builtin_amdgcn_global_load_lds((const __attribute__((address_space(1))) void*)srcB,
          (__attribute__((address_space(3))) void*)&Bs[(c * 256 + wbase) * 8], 16, 0, 0);
    }
    __syncthreads();
    bf16x8 a[4], b[4];
    #pragma unroll
    for (int i = 0; i < 4; ++i)
      a[i] = *reinterpret_cast<const bf16x8*>(&As[(wr * 64 + i * 16 + lr) * 32 + lh * 8]);
    #pragma unroll
    for (int j = 0; j < 4; ++j)
      b[j] = *reinterpret_cast<const bf16x8*>(&Bs[(wc * 64 + j * 16 + lr) * 32 + lh * 8]);
    #pragma unroll
    for (int i = 0; i < 4; ++i)
      #pragma unroll
      for (int j = 0; j < 4; ++j)
        acc[i][j] = __builtin_amdgcn_mfma_f32_16x16x32_bf16(a[i], b[j], acc[i][j], 0, 0, 0);
    __syncthreads();
  }

  #pragma unroll
  for (int i = 0; i < 4; ++i) {
    #pragma unroll
    for (int j = 0; j < 4; ++j) {
      int n = n0 + wc * 64 + j * 16 + lr;
      float bv = bias[n];
      #pragma unroll
      for (int r = 0; r < 4; ++r) {
        int m = m0 + wr * 64 + i * 16 + lh * 4 + r;
        out[(size_t)m * 1024 + n] = acc[i][j][r] + bv;
      }
    }
  }
}

// ---------------- launcher ----------------

extern "C" void kernel_launch(void* const* d_in, const int* in_sizes, int n_in,
                              void* d_out, int out_size, void* d_ws, size_t ws_size,
                              hipStream_t stream) {
  const float* x      = (const float*)d_in[0];
  const float* w_attn = (const float*)d_in[1];
  const float* b_attn = (const float*)d_in[2];
  const float* w_proj = (const float*)d_in[3];
  const float* b_proj = (const float*)d_in[4];
  float* out = (float*)d_out;

  char* ws = (char*)d_ws;
  unsigned short* xb  = (unsigned short*)(ws);                       // 16 MB  [8192][1024]
  unsigned short* wAT = (unsigned short*)(ws + 16777216);            // 6 MB   [3072][1024]
  unsigned short* wPT = (unsigned short*)(ws + 23068672);            // 2 MB   [1024][1024]
  unsigned short* Qb  = (unsigned short*)(ws + 25165824);            // 16 MB  [64][2048][64]
  unsigned short* Kb  = (unsigned short*)(ws + 41943040);            // 16 MB
  unsigned short* Vt  = (unsigned short*)(ws + 58720256);            // 16 MB  [64][64][2048]
  unsigned short* AO  = (unsigned short*)(ws + 75497472);            // 16 MB  [8192][1024]

  conv_x_bf16<<<(BT * CH / 4 + 255) / 256, 256, 0, stream>>>(x, xb, BT * CH / 4);
  transpose_w_bf16<<<dim3(3 * CH / 32, CH / 32), dim3(32, 8), 0, stream>>>(w_attn, wAT, CH, 3 * CH);
  transpose_w_bf16<<<dim3(CH / 32, CH / 32), dim3(32, 8), 0, stream>>>(w_proj, wPT, CH, CH);
  gemm_qkv<<<dim3(BT / 128, 3 * CH / 128), 256, 0, stream>>>(xb, wAT, b_attn, Qb, Kb, Vt);
  attn_fwd<<<512, 512, 0, stream>>>(Qb, Kb, Vt, AO);
  gemm_proj<<<dim3(BT / 128, CH / 128), 256, 0, stream>>>(AO, wPT, b_proj, out);
}

// Round 4
// 175.813 us; speedup vs baseline: 2.2510x; 1.0551x over previous
//
#include <hip/hip_runtime.h>
#include <hip/hip_bf16.h>

// Problem constants: B=4, T=2048, C=1024, H=16, D=64
#define BATCH 4
#define SEQ   2048
#define CH    1024
#define NH    16
#define HD    64
#define BT    8192   // BATCH*SEQ

typedef __attribute__((ext_vector_type(8))) short bf16x8;
typedef __attribute__((ext_vector_type(4))) float f32x4;
typedef __attribute__((ext_vector_type(16))) float f32x16;

__device__ __forceinline__ unsigned short f2b(float f) {
  __hip_bfloat16 h = __float2bfloat16(f);
  return *reinterpret_cast<unsigned short*>(&h);
}

__device__ __forceinline__ unsigned cvt_pk(float lo, float hi_) {
  unsigned r;
  asm("v_cvt_pk_bf16_f32 %0, %1, %2" : "=v"(r) : "v"(lo), "v"(hi_));
  return r;
}
// swap: a' = [a_lo | b_lo], b' = [a_hi | b_hi]
__device__ __forceinline__ void plane_swap(unsigned &a, unsigned &b) {
  asm("v_permlane32_swap_b32 %0, %1" : "+v"(a), "+v"(b));
}

// ---------------- conversion kernels ----------------

__global__ void conv_x_bf16(const float* __restrict__ in, unsigned short* __restrict__ out, int n4) {
  int i = blockIdx.x * blockDim.x + threadIdx.x;
  if (i >= n4) return;
  float4 v = reinterpret_cast<const float4*>(in)[i];
  ushort4 o;
  o.x = f2b(v.x); o.y = f2b(v.y); o.z = f2b(v.z); o.w = f2b(v.w);
  reinterpret_cast<ushort4*>(out)[i] = o;
}

// in[R][Cc] f32  ->  out[Cc][R] bf16
__global__ void transpose_w_bf16(const float* __restrict__ in, unsigned short* __restrict__ out,
                                 int R, int Cc) {
  __shared__ float tile[32][33];
  int c0 = blockIdx.x * 32, r0 = blockIdx.y * 32;
  int tx = threadIdx.x, ty = threadIdx.y;
  #pragma unroll
  for (int i = 0; i < 32; i += 8)
    tile[ty + i][tx] = in[(size_t)(r0 + ty + i) * Cc + c0 + tx];
  __syncthreads();
  #pragma unroll
  for (int i = 0; i < 32; i += 8)
    out[(size_t)(c0 + ty + i) * R + r0 + tx] = f2b(tile[tx][ty + i]);
}

// ---------------- GEMM1: qkv = x @ w_attn + b, scatter to Q/K/Vt ----------------
// Double-buffered LDS, one barrier per K-step (T3 minimum 2-phase).
// Epilogue: which is block-uniform; Q/K direct 32B-coalesced stores;
// V via LDS-bounce transpose -> 16B-coalesced stores to Vt[d][t].

#define QSCALE 0.18033688011112042f   // 0.125 * log2(e)

// stage A-tile [128][32] and B-tile [128][32] into buffer BUF of sb
#define GSTAGE(BUF, K0)                                                                        \
  {                                                                                            \
    _Pragma("unroll")                                                                          \
    for (int c = 0; c < 2; ++c) {                                                              \
      int idx = c * 256 + tid;                                                                 \
      const unsigned short* sA = A + (size_t)(m0 + (idx >> 2)) * 1024 + (K0) + (idx & 3) * 8;  \
      __builtin_amdgcn_global_load_lds((const __attribute__((address_space(1))) void*)sA,      \
          (__attribute__((address_space(3))) void*)&sb[(BUF) * 4096 + (c * 256 + (tid & ~63)) * 8], 16, 0, 0); \
      const unsigned short* sB = Bt + (size_t)(n0 + (idx >> 2)) * 1024 + (K0) + (idx & 3) * 8; \
      __builtin_amdgcn_global_load_lds((const __attribute__((address_space(1))) void*)sB,      \
          (__attribute__((address_space(3))) void*)&sb[8192 + (BUF) * 4096 + (c * 256 + (tid & ~63)) * 8], 16, 0, 0); \
    }                                                                                          \
  }

__global__ __launch_bounds__(256) void gemm_qkv(
    const unsigned short* __restrict__ A,
    const unsigned short* __restrict__ Bt,
    const float* __restrict__ bias,
    unsigned short* __restrict__ Qb,
    unsigned short* __restrict__ Kb,
    unsigned short* __restrict__ Vt) {
  // shorts: As0 [0,4096) | As1 [4096,8192) | Bs0 [8192,12288) | Bs1 [12288,16384)
  __shared__ __align__(16) unsigned short sb[16384];
  int tid = threadIdx.x;
  int lane = tid & 63, wav = tid >> 6;
  int wr = wav >> 1, wc = wav & 1;
  int lr = lane & 15, lh = lane >> 4;
  int m0 = blockIdx.x * 128, n0 = blockIdx.y * 128;

  f32x4 acc[4][4];
  #pragma unroll
  for (int i = 0; i < 4; ++i)
    #pragma unroll
    for (int j = 0; j < 4; ++j)
      acc[i][j] = f32x4{0.f, 0.f, 0.f, 0.f};

  GSTAGE(0, 0)
  asm volatile("s_waitcnt vmcnt(0)" ::: "memory");
  __builtin_amdgcn_s_barrier();

  int cur = 0;
  for (int k0 = 0; k0 < 1024; k0 += 32) {
    if (k0 + 32 < 1024) GSTAGE(cur ^ 1, k0 + 32)
    bf16x8 a[4], b[4];
    #pragma unroll
    for (int i = 0; i < 4; ++i)
      a[i] = *reinterpret_cast<const bf16x8*>(&sb[cur * 4096 + (wr * 64 + i * 16 + lr) * 32 + lh * 8]);
    #pragma unroll
    for (int j = 0; j < 4; ++j)
      b[j] = *reinterpret_cast<const bf16x8*>(&sb[8192 + cur * 4096 + (wc * 64 + j * 16 + lr) * 32 + lh * 8]);
    #pragma unroll
    for (int i = 0; i < 4; ++i)
      #pragma unroll
      for (int j = 0; j < 4; ++j)
        acc[i][j] = __builtin_amdgcn_mfma_f32_16x16x32_bf16(a[i], b[j], acc[i][j], 0, 0, 0);
    asm volatile("s_waitcnt vmcnt(0)" ::: "memory");
    __builtin_amdgcn_s_barrier();
    cur ^= 1;
  }

  // ---- epilogue (which, h2, bb, t0 all block-uniform) ----
  int which = n0 >> 10;            // 0:Q 1:K 2:V
  int h2 = (n0 >> 6) & 15;         // first head in block; block spans h2 (wc=0), h2+1 (wc=1)
  int bb = m0 >> 11, t0 = m0 & 2047;

  if (which < 2) {
    unsigned short* dst = which ? Kb : Qb;
    float sc = which ? 1.0f : QSCALE;
    size_t headbase = (size_t)(bb * 16 + h2 + wc) * SEQ;
    #pragma unroll
    for (int j = 0; j < 4; ++j) {
      int d = j * 16 + lr;
      float bv = bias[n0 + wc * 64 + d];
      #pragma unroll
      for (int i = 0; i < 4; ++i) {
        #pragma unroll
        for (int r = 0; r < 4; ++r) {
          int t = t0 + wr * 64 + i * 16 + lh * 4 + r;
          dst[(headbase + t) * HD + d] = f2b((acc[i][j][r] + bv) * sc);
        }
      }
    }
  } else {
    // V: bounce through LDS transposed [d][t] in two 64-d halves (16KB each)
    unsigned short* tile = sb;
    #pragma unroll
    for (int half = 0; half < 2; ++half) {
      if (wc == half) {
        #pragma unroll
        for (int j = 0; j < 4; ++j) {
          int nrow = j * 16 + lr;            // d within half
          float bv = bias[n0 + half * 64 + nrow];
          int sw = nrow & 7;
          #pragma unroll
          for (int i = 0; i < 4; ++i) {
            int cm = wr * 16 + i * 4 + lh;   // 8B chunk index along m (0..31)
            unsigned lo = cvt_pk(acc[i][j][0] + bv, acc[i][j][1] + bv);
            unsigned hi_ = cvt_pk(acc[i][j][2] + bv, acc[i][j][3] + bv);
            unsigned long long val = (unsigned long long)lo | ((unsigned long long)hi_ << 32);
            *reinterpret_cast<unsigned long long*>(&tile[nrow * 128 + (cm ^ sw) * 4]) = val;
          }
        }
      }
      __syncthreads();
      // read back + coalesced 16B stores: Vt[(bb*16+h2+half)*64 + d][t0 + p*8 ..]
      size_t vbase = (size_t)((bb * 16 + h2 + half) * 64);
      #pragma unroll
      for (int it = 0; it < 4; ++it) {
        int pid = it * 256 + tid;
        int nrow = pid >> 4, p = pid & 15;
        int sw = nrow & 7;
        union { unsigned long long u[2]; bf16x8 v; } u;
        u.u[0] = *reinterpret_cast<const unsigned long long*>(&tile[nrow * 128 + ((2 * p) ^ sw) * 4]);
        u.u[1] = *reinterpret_cast<const unsigned long long*>(&tile[nrow * 128 + (((2 * p) ^ sw) ^ 1) * 4]);
        *reinterpret_cast<bf16x8*>(&Vt[(vbase + nrow) * SEQ + t0 + p * 8]) = u.v;
      }
      __syncthreads();
    }
  }
}

// ---------------- flash attention (causal), 8-wave 32x32 swapped-operand ----------------

__global__ __launch_bounds__(512, 2) void attn_fwd(
    const unsigned short* __restrict__ Qb,
    const unsigned short* __restrict__ Kb,
    const unsigned short* __restrict__ Vt,
    unsigned short* __restrict__ AO) {
  __shared__ __align__(16) unsigned short sbuf[16384];

  int tid = threadIdx.x;
  int lane = tid & 63, w = tid >> 6;
  int ql = lane & 31, hi = lane >> 5;
  int bid = blockIdx.x;
  int head = bid & 63;
  int qs = 7 - (bid >> 6);          // heavy q-slots dispatched first
  int q0 = qs * 256;
  int nt = 4 * (qs + 1);            // kv tiles of 64
  int b = head >> 4, h = head & 15;

  const unsigned short* Qh = Qb + (size_t)head * SEQ * HD;
  const unsigned short* Kh = Kb + (size_t)head * SEQ * HD;
  const unsigned short* Vh = Vt + (size_t)head * HD * SEQ;

#define STAGE(BUF, KV0)                                                                        \
  {                                                                                            \
    int row_ = tid >> 3;                                                                       \
    int cg_ = (tid & 7) ^ (row_ & 7);                                                          \
    const unsigned short* srcK_ = Kh + (size_t)((KV0) + row_) * HD + cg_ * 8;                  \
    __builtin_amdgcn_global_load_lds((const __attribute__((address_space(1))) void*)srcK_,     \
        (__attribute__((address_space(3))) void*)&sbuf[(BUF) * 4096 + (tid & ~63) * 8], 16, 0, 0); \
    const unsigned short* srcV_ = Vh + (size_t)row_ * SEQ + (KV0) + cg_ * 8;                   \
    __builtin_amdgcn_global_load_lds((const __attribute__((address_space(1))) void*)srcV_,     \
        (__attribute__((address_space(3))) void*)&sbuf[8192 + (BUF) * 4096 + (tid & ~63) * 8], 16, 0, 0); \
  }

  int qg = q0 + w * 32 + ql;
  bf16x8 qf[4];
  #pragma unroll
  for (int dblk = 0; dblk < 4; ++dblk)
    qf[dblk] = *reinterpret_cast<const bf16x8*>(&Qh[(size_t)qg * HD + dblk * 16 + hi * 8]);

  f32x16 o0 = (f32x16)0.0f, o1 = (f32x16)0.0f;   // O^T: rows=d (2 blocks), col=q=ql
  float mrun = -1e30f, lrun = 0.f;

  STAGE(0, 0)
  asm volatile("s_waitcnt vmcnt(0)" ::: "memory");
  __builtin_amdgcn_s_barrier();

  int cur = 0;
  int wq_hi = q0 + w * 32 + 31;
  for (int t = 0; t < nt; ++t) {
    int kv0 = t * 64;
    if (t + 1 < nt) STAGE(cur ^ 1, kv0 + 64)

    if (kv0 <= wq_hi) {
      // ---- S^T = K·Q^T : C[kv][q], col=q=ql, rows=kv via (reg,hi) ----
      f32x16 s0 = (f32x16)0.0f, s1 = (f32x16)0.0f;
      int rk0 = ql, rk1 = 32 + ql;
      __builtin_amdgcn_s_setprio(1);
      #pragma unroll
      for (int dblk = 0; dblk < 4; ++dblk) {
        bf16x8 kf0 = *reinterpret_cast<const bf16x8*>(
            &sbuf[cur * 4096 + rk0 * 64 + (((dblk * 2 + hi) ^ (rk0 & 7)) << 3)]);
        s0 = __builtin_amdgcn_mfma_f32_32x32x16_bf16(kf0, qf[dblk], s0, 0, 0, 0);
        bf16x8 kf1 = *reinterpret_cast<const bf16x8*>(
            &sbuf[cur * 4096 + rk1 * 64 + (((dblk * 2 + hi) ^ (rk1 & 7)) << 3)]);
        s1 = __builtin_amdgcn_mfma_f32_32x32x16_bf16(kf1, qf[dblk], s1, 0, 0, 0);
      }
      __builtin_amdgcn_s_setprio(0);

      // ---- mask + gather into p[32] (kv = kv0 + 32*blk + cr + 4*hi) ----
      float p[32];
      bool needMask = (kv0 + 63 > q0 + 32 * w);
      #pragma unroll
      for (int r = 0; r < 16; ++r) {
        int cr = (r & 3) + 8 * (r >> 2);
        float v0 = s0[r], v1 = s1[r];
        if (needMask) {
          int kv_ = kv0 + 4 * hi + cr;
          v0 = (kv_ > qg) ? -1e30f : v0;
          v1 = (kv_ + 32 > qg) ? -1e30f : v1;
        }
        p[r] = v0; p[16 + r] = v1;
      }

      // ---- row max ----
      float m16[16], m8[8], m4[4], m2[2];
      #pragma unroll
      for (int i = 0; i < 16; ++i) m16[i] = fmaxf(p[i], p[i + 16]);
      #pragma unroll
      for (int i = 0; i < 8; ++i) m8[i] = fmaxf(m16[i], m16[i + 8]);
      #pragma unroll
      for (int i = 0; i < 4; ++i) m4[i] = fmaxf(m8[i], m8[i + 4]);
      m2[0] = fmaxf(m4[0], m4[2]); m2[1] = fmaxf(m4[1], m4[3]);
      float mt = fmaxf(m2[0], m2[1]);
      mt = fmaxf(mt, __shfl_xor(mt, 32));
      float mnew = fmaxf(mrun, mt);
      float alpha = __builtin_amdgcn_exp2f(mrun - mnew);
      mrun = mnew;

      // ---- p = exp2(s - m), row sum ----
      #pragma unroll
      for (int i = 0; i < 32; ++i) p[i] = __builtin_amdgcn_exp2f(p[i] - mnew);
      float a16[16], a8[8], a4[4];
      #pragma unroll
      for (int i = 0; i < 16; ++i) a16[i] = p[i] + p[i + 16];
      #pragma unroll
      for (int i = 0; i < 8; ++i) a8[i] = a16[i] + a16[i + 8];
      #pragma unroll
      for (int i = 0; i < 4; ++i) a4[i] = a8[i] + a8[i + 4];
      float rs = (a4[0] + a4[1]) + (a4[2] + a4[3]);
      rs += __shfl_xor(rs, 32);
      lrun = lrun * alpha + rs;

      #pragma unroll
      for (int i = 0; i < 16; ++i) { o0[i] *= alpha; o1[i] *= alpha; }

      // ---- P -> B-fragments: 16 cvt_pk + 8 permlane32_swap (T12) ----
      union FU { unsigned u[4]; bf16x8 v; };
      FU fr[4];
      #pragma unroll
      for (int blk = 0; blk < 2; ++blk) {
        unsigned X = cvt_pk(p[blk * 16 + 0], p[blk * 16 + 1]);
        unsigned Z = cvt_pk(p[blk * 16 + 4], p[blk * 16 + 5]);
        plane_swap(X, Z);
        unsigned Y = cvt_pk(p[blk * 16 + 2], p[blk * 16 + 3]);
        unsigned W = cvt_pk(p[blk * 16 + 6], p[blk * 16 + 7]);
        plane_swap(Y, W);
        fr[blk * 2].u[0] = X; fr[blk * 2].u[1] = Y; fr[blk * 2].u[2] = Z; fr[blk * 2].u[3] = W;
        unsigned X2 = cvt_pk(p[blk * 16 + 8], p[blk * 16 + 9]);
        unsigned Z2 = cvt_pk(p[blk * 16 + 12], p[blk * 16 + 13]);
        plane_swap(X2, Z2);
        unsigned Y2 = cvt_pk(p[blk * 16 + 10], p[blk * 16 + 11]);
        unsigned W2 = cvt_pk(p[blk * 16 + 14], p[blk * 16 + 15]);
        plane_swap(Y2, W2);
        fr[blk * 2 + 1].u[0] = X2; fr[blk * 2 + 1].u[1] = Y2;
        fr[blk * 2 + 1].u[2] = Z2; fr[blk * 2 + 1].u[3] = W2;
      }

      // ---- O^T += V^T · P : C[d][q] ----
      __builtin_amdgcn_s_setprio(1);
      #pragma unroll
      for (int kc = 0; kc < 4; ++kc) {
        int rd0 = ql, rd1 = 32 + ql;
        bf16x8 vf0 = *reinterpret_cast<const bf16x8*>(
            &sbuf[8192 + cur * 4096 + rd0 * 64 + ((((kc << 1) + hi) ^ (rd0 & 7)) << 3)]);
        o0 = __builtin_amdgcn_mfma_f32_32x32x16_bf16(vf0, fr[kc].v, o0, 0, 0, 0);
        bf16x8 vf1 = *reinterpret_cast<const bf16x8*>(
            &sbuf[8192 + cur * 4096 + rd1 * 64 + ((((kc << 1) + hi) ^ (rd1 & 7)) << 3)]);
        o1 = __builtin_amdgcn_mfma_f32_32x32x16_bf16(vf1, fr[kc].v, o1, 0, 0, 0);
      }
      __builtin_amdgcn_s_setprio(0);
    }

    asm volatile("s_waitcnt vmcnt(0)" ::: "memory");
    __builtin_amdgcn_s_barrier();
    cur ^= 1;
  }

  // ---- epilogue: normalize, LDS-bounce transpose, coalesced store ----
  float inv = 1.0f / lrun;
  int qloc = w * 32 + ql;
  #pragma unroll
  for (int dblk = 0; dblk < 2; ++dblk) {
    #pragma unroll
    for (int m = 0; m < 4; ++m) {
      float v0, v1, v2, v3;
      if (dblk == 0) {
        v0 = o0[m * 4 + 0] * inv; v1 = o0[m * 4 + 1] * inv;
        v2 = o0[m * 4 + 2] * inv; v3 = o0[m * 4 + 3] * inv;
      } else {
        v0 = o1[m * 4 + 0] * inv; v1 = o1[m * 4 + 1] * inv;
        v2 = o1[m * 4 + 2] * inv; v3 = o1[m * 4 + 3] * inv;
      }
      unsigned u0 = (unsigned)f2b(v0) | ((unsigned)f2b(v1) << 16);
      unsigned u1 = (unsigned)f2b(v2) | ((unsigned)f2b(v3) << 16);
      int slot = (dblk * 4 + m) ^ (qloc & 7);
      unsigned long long val = (unsigned long long)u0 | ((unsigned long long)u1 << 32);
      *reinterpret_cast<unsigned long long*>(&sbuf[qloc * 64 + slot * 8 + hi * 4]) = val;
    }
  }
  __syncthreads();

  #pragma unroll
  for (int it = 0; it < 4; ++it) {
    int qr = it * 64 + (tid >> 3);
    int lc = tid & 7;
    int slot = lc ^ (qr & 7);
    bf16x8 v = *reinterpret_cast<const bf16x8*>(&sbuf[qr * 64 + slot * 8]);
    *reinterpret_cast<bf16x8*>(
        &AO[(size_t)(b * SEQ + q0 + qr) * CH + h * 64 + lc * 8]) = v;
  }
}

// ---------------- GEMM2: out = AO @ w_proj + b (fp32 out) ----------------

__global__ __launch_bounds__(256) void gemm_proj(
    const unsigned short* __restrict__ A,   // [8192][1024]
    const unsigned short* __restrict__ Bt,  // [1024][1024]
    const float* __restrict__ bias,
    float* __restrict__ out) {
  __shared__ __align__(16) unsigned short sb[16384];
  int tid = threadIdx.x;
  int lane = tid & 63, wav = tid >> 6;
  int wr = wav >> 1, wc = wav & 1;
  int lr = lane & 15, lh = lane >> 4;
  int m0 = blockIdx.x * 128, n0 = blockIdx.y * 128;

  f32x4 acc[4][4];
  #pragma unroll
  for (int i = 0; i < 4; ++i)
    #pragma unroll
    for (int j = 0; j < 4; ++j)
      acc[i][j] = f32x4{0.f, 0.f, 0.f, 0.f};

  GSTAGE(0, 0)
  asm volatile("s_waitcnt vmcnt(0)" ::: "memory");
  __builtin_amdgcn_s_barrier();

  int cur = 0;
  for (int k0 = 0; k0 < 1024; k0 += 32) {
    if (k0 + 32 < 1024) GSTAGE(cur ^ 1, k0 + 32)
    bf16x8 a[4], b[4];
    #pragma unroll
    for (int i = 0; i < 4; ++i)
      a[i] = *reinterpret_cast<const bf16x8*>(&sb[cur * 4096 + (wr * 64 + i * 16 + lr) * 32 + lh * 8]);
    #pragma unroll
    for (int j = 0; j < 4; ++j)
      b[j] = *reinterpret_cast<const bf16x8*>(&sb[8192 + cur * 4096 + (wc * 64 + j * 16 + lr) * 32 + lh * 8]);
    #pragma unroll
    for (int i = 0; i < 4; ++i)
      #pragma unroll
      for (int j = 0; j < 4; ++j)
        acc[i][j] = __builtin_amdgcn_mfma_f32_16x16x32_bf16(a[i], b[j], acc[i][j], 0, 0, 0);
    asm volatile("s_waitcnt vmcnt(0)" ::: "memory");
    __builtin_amdgcn_s_barrier();
    cur ^= 1;
  }

  #pragma unroll
  for (int i = 0; i < 4; ++i) {
    #pragma unroll
    for (int j = 0; j < 4; ++j) {
      int n = n0 + wc * 64 + j * 16 + lr;
      float bv = bias[n];
      #pragma unroll
      for (int r = 0; r < 4; ++r) {
        int m = m0 + wr * 64 + i * 16 + lh * 4 + r;
        out[(size_t)m * 1024 + n] = acc[i][j][r] + bv;
      }
    }
  }
}

// ---------------- launcher ----------------

extern "C" void kernel_launch(void* const* d_in, const int* in_sizes, int n_in,
                              void* d_out, int out_size, void* d_ws, size_t ws_size,
                              hipStream_t stream) {
  const float* x      = (const float*)d_in[0];
  const float* w_attn = (const float*)d_in[1];
  const float* b_attn = (const float*)d_in[2];
  const float* w_proj = (const float*)d_in[3];
  const float* b_proj = (const float*)d_in[4];
  float* out = (float*)d_out;

  char* ws = (char*)d_ws;
  unsigned short* xb  = (unsigned short*)(ws);                       // 16 MB  [8192][1024]
  unsigned short* wAT = (unsigned short*)(ws + 16777216);            // 6 MB   [3072][1024]
  unsigned short* wPT = (unsigned short*)(ws + 23068672);            // 2 MB   [1024][1024]
  unsigned short* Qb  = (unsigned short*)(ws + 25165824);            // 16 MB  [64][2048][64]
  unsigned short* Kb  = (unsigned short*)(ws + 41943040);            // 16 MB
  unsigned short* Vt  = (unsigned short*)(ws + 58720256);            // 16 MB  [64][64][2048]
  unsigned short* AO  = (unsigned short*)(ws + 75497472);            // 16 MB  [8192][1024]

  conv_x_bf16<<<(BT * CH / 4 + 255) / 256, 256, 0, stream>>>(x, xb, BT * CH / 4);
  transpose_w_bf16<<<dim3(3 * CH / 32, CH / 32), dim3(32, 8), 0, stream>>>(w_attn, wAT, CH, 3 * CH);
  transpose_w_bf16<<<dim3(CH / 32, CH / 32), dim3(32, 8), 0, stream>>>(w_proj, wPT, CH, CH);
  gemm_qkv<<<dim3(BT / 128, 3 * CH / 128), 256, 0, stream>>>(xb, wAT, b_attn, Qb, Kb, Vt);
  attn_fwd<<<512, 512, 0, stream>>>(Qb, Kb, Vt, AO);
  gemm_proj<<<dim3(BT / 128, CH / 128), 256, 0, stream>>>(AO, wPT, b_proj, out);
}

// Round 5
// 170.948 us; speedup vs baseline: 2.3150x; 1.0285x over previous
//
#include <hip/hip_runtime.h>
#include <hip/hip_bf16.h>

// Problem constants: B=4, T=2048, C=1024, H=16, D=64
#define BATCH 4
#define SEQ   2048
#define CH    1024
#define NH    16
#define HD    64
#define BT    8192   // BATCH*SEQ

typedef __attribute__((ext_vector_type(8))) short bf16x8;
typedef __attribute__((ext_vector_type(4))) float f32x4;
typedef __attribute__((ext_vector_type(16))) float f32x16;

__device__ __forceinline__ unsigned short f2b(float f) {
  __hip_bfloat16 h = __float2bfloat16(f);
  return *reinterpret_cast<unsigned short*>(&h);
}

__device__ __forceinline__ unsigned cvt_pk(float lo, float hi_) {
  unsigned r;
  asm("v_cvt_pk_bf16_f32 %0, %1, %2" : "=v"(r) : "v"(lo), "v"(hi_));
  return r;
}
// swap: a' = [a_lo | b_lo], b' = [a_hi | b_hi]
__device__ __forceinline__ void plane_swap(unsigned &a, unsigned &b) {
  asm("v_permlane32_swap_b32 %0, %1" : "+v"(a), "+v"(b));
}

// ---------------- conversion kernels ----------------

__global__ void conv_x_bf16(const float* __restrict__ in, unsigned short* __restrict__ out, int n4) {
  int i = blockIdx.x * blockDim.x + threadIdx.x;
  if (i >= n4) return;
  float4 v = reinterpret_cast<const float4*>(in)[i];
  ushort4 o;
  o.x = f2b(v.x); o.y = f2b(v.y); o.z = f2b(v.z); o.w = f2b(v.w);
  reinterpret_cast<ushort4*>(out)[i] = o;
}

// in[R][Cc] f32  ->  out[Cc][R] bf16
__global__ void transpose_w_bf16(const float* __restrict__ in, unsigned short* __restrict__ out,
                                 int R, int Cc) {
  __shared__ float tile[32][33];
  int c0 = blockIdx.x * 32, r0 = blockIdx.y * 32;
  int tx = threadIdx.x, ty = threadIdx.y;
  #pragma unroll
  for (int i = 0; i < 32; i += 8)
    tile[ty + i][tx] = in[(size_t)(r0 + ty + i) * Cc + c0 + tx];
  __syncthreads();
  #pragma unroll
  for (int i = 0; i < 32; i += 8)
    out[(size_t)(c0 + ty + i) * R + r0 + tx] = f2b(tile[tx][ty + i]);
}

// ---------------- GEMM1: qkv = x @ w_attn + b, scatter to Q/K/Vt ----------------
// 3-buffer LDS pipeline, counted vmcnt (T4): tile t+2's loads stay in flight
// across the barrier; wait only for tile t+1 (vmcnt(4) = 8 outstanding - 4 oldest).

#define QSCALE 0.18033688011112042f   // 0.125 * log2(e)

// LDS layout (shorts): A bufs [buf*4096, buf 0..2) ; B bufs [12288 + buf*4096)
#define GSTAGE(BUF, K0)                                                                        \
  {                                                                                            \
    _Pragma("unroll")                                                                          \
    for (int c = 0; c < 2; ++c) {                                                              \
      int idx = c * 256 + tid;                                                                 \
      const unsigned short* sA = A + (size_t)(m0 + (idx >> 2)) * 1024 + (K0) + (idx & 3) * 8;  \
      __builtin_amdgcn_global_load_lds((const __attribute__((address_space(1))) void*)sA,      \
          (__attribute__((address_space(3))) void*)&sb[(BUF) * 4096 + (c * 256 + (tid & ~63)) * 8], 16, 0, 0); \
      const unsigned short* sB = Bt + (size_t)(n0 + (idx >> 2)) * 1024 + (K0) + (idx & 3) * 8; \
      __builtin_amdgcn_global_load_lds((const __attribute__((address_space(1))) void*)sB,      \
          (__attribute__((address_space(3))) void*)&sb[12288 + (BUF) * 4096 + (c * 256 + (tid & ~63)) * 8], 16, 0, 0); \
    }                                                                                          \
  }

__global__ __launch_bounds__(256) void gemm_qkv(
    const unsigned short* __restrict__ A,
    const unsigned short* __restrict__ Bt,
    const float* __restrict__ bias,
    unsigned short* __restrict__ Qb,
    unsigned short* __restrict__ Kb,
    unsigned short* __restrict__ Vt) {
  __shared__ __align__(16) unsigned short sb[24576];   // 48 KB: 3xA + 3xB
  int tid = threadIdx.x;
  int lane = tid & 63, wav = tid >> 6;
  int wr = wav >> 1, wc = wav & 1;
  int lr = lane & 15, lh = lane >> 4;
  int m0 = blockIdx.x * 128, n0 = blockIdx.y * 128;

  f32x4 acc[4][4];
  #pragma unroll
  for (int i = 0; i < 4; ++i)
    #pragma unroll
    for (int j = 0; j < 4; ++j)
      acc[i][j] = f32x4{0.f, 0.f, 0.f, 0.f};

  GSTAGE(0, 0)
  GSTAGE(1, 32)
  asm volatile("s_waitcnt vmcnt(4)" ::: "memory");
  __builtin_amdgcn_s_barrier();

  int cur = 0;
  for (int k0 = 0; k0 < 1024; k0 += 32) {
    bool issued = (k0 + 64 < 1024);
    int nb = cur + 2; if (nb >= 3) nb -= 3;
    if (issued) GSTAGE(nb, k0 + 64)
    bf16x8 a[4], b[4];
    #pragma unroll
    for (int i = 0; i < 4; ++i)
      a[i] = *reinterpret_cast<const bf16x8*>(&sb[cur * 4096 + (wr * 64 + i * 16 + lr) * 32 + lh * 8]);
    #pragma unroll
    for (int j = 0; j < 4; ++j)
      b[j] = *reinterpret_cast<const bf16x8*>(&sb[12288 + cur * 4096 + (wc * 64 + j * 16 + lr) * 32 + lh * 8]);
    #pragma unroll
    for (int i = 0; i < 4; ++i)
      #pragma unroll
      for (int j = 0; j < 4; ++j)
        acc[i][j] = __builtin_amdgcn_mfma_f32_16x16x32_bf16(a[i], b[j], acc[i][j], 0, 0, 0);
    if (issued) { asm volatile("s_waitcnt vmcnt(4)" ::: "memory"); }
    else        { asm volatile("s_waitcnt vmcnt(0)" ::: "memory"); }
    __builtin_amdgcn_s_barrier();
    cur = (cur + 1 == 3) ? 0 : cur + 1;
  }

  // ---- epilogue (which, h2, bb, t0 all block-uniform) ----
  int which = n0 >> 10;            // 0:Q 1:K 2:V
  int h2 = (n0 >> 6) & 15;         // first head in block; block spans h2 (wc=0), h2+1 (wc=1)
  int bb = m0 >> 11, t0 = m0 & 2047;

  if (which < 2) {
    unsigned short* dst = which ? Kb : Qb;
    float sc = which ? 1.0f : QSCALE;
    size_t headbase = (size_t)(bb * 16 + h2 + wc) * SEQ;
    #pragma unroll
    for (int j = 0; j < 4; ++j) {
      int d = j * 16 + lr;
      float bv = bias[n0 + wc * 64 + d];
      #pragma unroll
      for (int i = 0; i < 4; ++i) {
        #pragma unroll
        for (int r = 0; r < 4; ++r) {
          int t = t0 + wr * 64 + i * 16 + lh * 4 + r;
          dst[(headbase + t) * HD + d] = f2b((acc[i][j][r] + bv) * sc);
        }
      }
    }
  } else {
    // V: bounce through LDS transposed [d][t] in two 64-d halves
    unsigned short* tile = sb;
    #pragma unroll
    for (int half = 0; half < 2; ++half) {
      if (wc == half) {
        #pragma unroll
        for (int j = 0; j < 4; ++j) {
          int nrow = j * 16 + lr;            // d within half
          float bv = bias[n0 + half * 64 + nrow];
          int sw = nrow & 7;
          #pragma unroll
          for (int i = 0; i < 4; ++i) {
            int cm = wr * 16 + i * 4 + lh;   // 8B chunk index along m (0..31)
            unsigned lo = cvt_pk(acc[i][j][0] + bv, acc[i][j][1] + bv);
            unsigned hi_ = cvt_pk(acc[i][j][2] + bv, acc[i][j][3] + bv);
            unsigned long long val = (unsigned long long)lo | ((unsigned long long)hi_ << 32);
            *reinterpret_cast<unsigned long long*>(&tile[nrow * 128 + (cm ^ sw) * 4]) = val;
          }
        }
      }
      __syncthreads();
      size_t vbase = (size_t)((bb * 16 + h2 + half) * 64);
      #pragma unroll
      for (int it = 0; it < 4; ++it) {
        int pid = it * 256 + tid;
        int nrow = pid >> 4, p = pid & 15;
        int sw = nrow & 7;
        union { unsigned long long u[2]; bf16x8 v; } u;
        u.u[0] = *reinterpret_cast<const unsigned long long*>(&tile[nrow * 128 + ((2 * p) ^ sw) * 4]);
        u.u[1] = *reinterpret_cast<const unsigned long long*>(&tile[nrow * 128 + (((2 * p) ^ sw) ^ 1) * 4]);
        *reinterpret_cast<bf16x8*>(&Vt[(vbase + nrow) * SEQ + t0 + p * 8]) = u.v;
      }
      __syncthreads();
    }
  }
}

// ---------------- flash attention (causal), 8-wave 32x32 swapped-operand ----------------
// 3-buffer K/V pipeline with counted vmcnt: STAGE = 2 loads; wait vmcnt(2)
// keeps tile t+2 in flight across the barrier.

__global__ __launch_bounds__(512, 2) void attn_fwd(
    const unsigned short* __restrict__ Qb,
    const unsigned short* __restrict__ Kb,
    const unsigned short* __restrict__ Vt,
    unsigned short* __restrict__ AO) {
  // shorts: K bufs [buf*4096, buf 0..2) ; V bufs [12288 + buf*4096) ; total 48 KB
  __shared__ __align__(16) unsigned short sbuf[24576];

  int tid = threadIdx.x;
  int lane = tid & 63, w = tid >> 6;
  int ql = lane & 31, hi = lane >> 5;
  int bid = blockIdx.x;
  int head = bid & 63;
  int qs = 7 - (bid >> 6);          // heavy q-slots dispatched first
  int q0 = qs * 256;
  int nt = 4 * (qs + 1);            // kv tiles of 64
  int b = head >> 4, h = head & 15;

  const unsigned short* Qh = Qb + (size_t)head * SEQ * HD;
  const unsigned short* Kh = Kb + (size_t)head * SEQ * HD;
  const unsigned short* Vh = Vt + (size_t)head * HD * SEQ;

#define STAGE(BUF, KV0)                                                                        \
  {                                                                                            \
    int row_ = tid >> 3;                                                                       \
    int cg_ = (tid & 7) ^ (row_ & 7);                                                          \
    const unsigned short* srcK_ = Kh + (size_t)((KV0) + row_) * HD + cg_ * 8;                  \
    __builtin_amdgcn_global_load_lds((const __attribute__((address_space(1))) void*)srcK_,     \
        (__attribute__((address_space(3))) void*)&sbuf[(BUF) * 4096 + (tid & ~63) * 8], 16, 0, 0); \
    const unsigned short* srcV_ = Vh + (size_t)row_ * SEQ + (KV0) + cg_ * 8;                   \
    __builtin_amdgcn_global_load_lds((const __attribute__((address_space(1))) void*)srcV_,     \
        (__attribute__((address_space(3))) void*)&sbuf[12288 + (BUF) * 4096 + (tid & ~63) * 8], 16, 0, 0); \
  }

  int qg = q0 + w * 32 + ql;
  bf16x8 qf[4];
  #pragma unroll
  for (int dblk = 0; dblk < 4; ++dblk)
    qf[dblk] = *reinterpret_cast<const bf16x8*>(&Qh[(size_t)qg * HD + dblk * 16 + hi * 8]);

  f32x16 o0 = (f32x16)0.0f, o1 = (f32x16)0.0f;   // O^T: rows=d (2 blocks), col=q=ql
  float mrun = -1e30f, lrun = 0.f;

  STAGE(0, 0)
  STAGE(1, 64)                       // nt >= 4 always
  asm volatile("s_waitcnt vmcnt(2)" ::: "memory");
  __builtin_amdgcn_s_barrier();

  int cur = 0;
  int wq_hi = q0 + w * 32 + 31;
  for (int t = 0; t < nt; ++t) {
    int kv0 = t * 64;
    bool issued = (t + 2 < nt);
    int nb = cur + 2; if (nb >= 3) nb -= 3;
    if (issued) STAGE(nb, kv0 + 128)

    if (kv0 <= wq_hi) {
      // ---- S^T = K·Q^T : C[kv][q], col=q=ql, rows=kv via (reg,hi) ----
      f32x16 s0 = (f32x16)0.0f, s1 = (f32x16)0.0f;
      int rk0 = ql, rk1 = 32 + ql;
      __builtin_amdgcn_s_setprio(1);
      #pragma unroll
      for (int dblk = 0; dblk < 4; ++dblk) {
        bf16x8 kf0 = *reinterpret_cast<const bf16x8*>(
            &sbuf[cur * 4096 + rk0 * 64 + (((dblk * 2 + hi) ^ (rk0 & 7)) << 3)]);
        s0 = __builtin_amdgcn_mfma_f32_32x32x16_bf16(kf0, qf[dblk], s0, 0, 0, 0);
        bf16x8 kf1 = *reinterpret_cast<const bf16x8*>(
            &sbuf[cur * 4096 + rk1 * 64 + (((dblk * 2 + hi) ^ (rk1 & 7)) << 3)]);
        s1 = __builtin_amdgcn_mfma_f32_32x32x16_bf16(kf1, qf[dblk], s1, 0, 0, 0);
      }
      __builtin_amdgcn_s_setprio(0);

      // ---- mask + gather into p[32] (kv = kv0 + 32*blk + cr + 4*hi) ----
      float p[32];
      bool needMask = (kv0 + 63 > q0 + 32 * w);
      #pragma unroll
      for (int r = 0; r < 16; ++r) {
        int cr = (r & 3) + 8 * (r >> 2);
        float v0 = s0[r], v1 = s1[r];
        if (needMask) {
          int kv_ = kv0 + 4 * hi + cr;
          v0 = (kv_ > qg) ? -1e30f : v0;
          v1 = (kv_ + 32 > qg) ? -1e30f : v1;
        }
        p[r] = v0; p[16 + r] = v1;
      }

      // ---- row max ----
      float m16[16], m8[8], m4[4], m2[2];
      #pragma unroll
      for (int i = 0; i < 16; ++i) m16[i] = fmaxf(p[i], p[i + 16]);
      #pragma unroll
      for (int i = 0; i < 8; ++i) m8[i] = fmaxf(m16[i], m16[i + 8]);
      #pragma unroll
      for (int i = 0; i < 4; ++i) m4[i] = fmaxf(m8[i], m8[i + 4]);
      m2[0] = fmaxf(m4[0], m4[2]); m2[1] = fmaxf(m4[1], m4[3]);
      float mt = fmaxf(m2[0], m2[1]);
      mt = fmaxf(mt, __shfl_xor(mt, 32));
      float mnew = fmaxf(mrun, mt);
      float alpha = __builtin_amdgcn_exp2f(mrun - mnew);
      mrun = mnew;

      // ---- p = exp2(s - m), row sum ----
      #pragma unroll
      for (int i = 0; i < 32; ++i) p[i] = __builtin_amdgcn_exp2f(p[i] - mnew);
      float a16[16], a8[8], a4[4];
      #pragma unroll
      for (int i = 0; i < 16; ++i) a16[i] = p[i] + p[i + 16];
      #pragma unroll
      for (int i = 0; i < 8; ++i) a8[i] = a16[i] + a16[i + 8];
      #pragma unroll
      for (int i = 0; i < 4; ++i) a4[i] = a8[i] + a8[i + 4];
      float rs = (a4[0] + a4[1]) + (a4[2] + a4[3]);
      rs += __shfl_xor(rs, 32);
      lrun = lrun * alpha + rs;

      #pragma unroll
      for (int i = 0; i < 16; ++i) { o0[i] *= alpha; o1[i] *= alpha; }

      // ---- P -> B-fragments: 16 cvt_pk + 8 permlane32_swap (T12) ----
      union FU { unsigned u[4]; bf16x8 v; };
      FU fr[4];
      #pragma unroll
      for (int blk = 0; blk < 2; ++blk) {
        unsigned X = cvt_pk(p[blk * 16 + 0], p[blk * 16 + 1]);
        unsigned Z = cvt_pk(p[blk * 16 + 4], p[blk * 16 + 5]);
        plane_swap(X, Z);
        unsigned Y = cvt_pk(p[blk * 16 + 2], p[blk * 16 + 3]);
        unsigned W = cvt_pk(p[blk * 16 + 6], p[blk * 16 + 7]);
        plane_swap(Y, W);
        fr[blk * 2].u[0] = X; fr[blk * 2].u[1] = Y; fr[blk * 2].u[2] = Z; fr[blk * 2].u[3] = W;
        unsigned X2 = cvt_pk(p[blk * 16 + 8], p[blk * 16 + 9]);
        unsigned Z2 = cvt_pk(p[blk * 16 + 12], p[blk * 16 + 13]);
        plane_swap(X2, Z2);
        unsigned Y2 = cvt_pk(p[blk * 16 + 10], p[blk * 16 + 11]);
        unsigned W2 = cvt_pk(p[blk * 16 + 14], p[blk * 16 + 15]);
        plane_swap(Y2, W2);
        fr[blk * 2 + 1].u[0] = X2; fr[blk * 2 + 1].u[1] = Y2;
        fr[blk * 2 + 1].u[2] = Z2; fr[blk * 2 + 1].u[3] = W2;
      }

      // ---- O^T += V^T · P : C[d][q] ----
      __builtin_amdgcn_s_setprio(1);
      #pragma unroll
      for (int kc = 0; kc < 4; ++kc) {
        int rd0 = ql, rd1 = 32 + ql;
        bf16x8 vf0 = *reinterpret_cast<const bf16x8*>(
            &sbuf[12288 + cur * 4096 + rd0 * 64 + ((((kc << 1) + hi) ^ (rd0 & 7)) << 3)]);
        o0 = __builtin_amdgcn_mfma_f32_32x32x16_bf16(vf0, fr[kc].v, o0, 0, 0, 0);
        bf16x8 vf1 = *reinterpret_cast<const bf16x8*>(
            &sbuf[12288 + cur * 4096 + rd1 * 64 + ((((kc << 1) + hi) ^ (rd1 & 7)) << 3)]);
        o1 = __builtin_amdgcn_mfma_f32_32x32x16_bf16(vf1, fr[kc].v, o1, 0, 0, 0);
      }
      __builtin_amdgcn_s_setprio(0);
    }

    if (issued) { asm volatile("s_waitcnt vmcnt(2)" ::: "memory"); }
    else        { asm volatile("s_waitcnt vmcnt(0)" ::: "memory"); }
    __builtin_amdgcn_s_barrier();
    cur = (cur + 1 == 3) ? 0 : cur + 1;
  }

  // ---- epilogue: normalize, LDS-bounce transpose, coalesced store ----
  float inv = 1.0f / lrun;
  int qloc = w * 32 + ql;
  #pragma unroll
  for (int dblk = 0; dblk < 2; ++dblk) {
    #pragma unroll
    for (int m = 0; m < 4; ++m) {
      float v0, v1, v2, v3;
      if (dblk == 0) {
        v0 = o0[m * 4 + 0] * inv; v1 = o0[m * 4 + 1] * inv;
        v2 = o0[m * 4 + 2] * inv; v3 = o0[m * 4 + 3] * inv;
      } else {
        v0 = o1[m * 4 + 0] * inv; v1 = o1[m * 4 + 1] * inv;
        v2 = o1[m * 4 + 2] * inv; v3 = o1[m * 4 + 3] * inv;
      }
      unsigned u0 = (unsigned)f2b(v0) | ((unsigned)f2b(v1) << 16);
      unsigned u1 = (unsigned)f2b(v2) | ((unsigned)f2b(v3) << 16);
      int slot = (dblk * 4 + m) ^ (qloc & 7);
      unsigned long long val = (unsigned long long)u0 | ((unsigned long long)u1 << 32);
      *reinterpret_cast<unsigned long long*>(&sbuf[qloc * 64 + slot * 8 + hi * 4]) = val;
    }
  }
  __syncthreads();

  #pragma unroll
  for (int it = 0; it < 4; ++it) {
    int qr = it * 64 + (tid >> 3);
    int lc = tid & 7;
    int slot = lc ^ (qr & 7);
    bf16x8 v = *reinterpret_cast<const bf16x8*>(&sbuf[qr * 64 + slot * 8]);
    *reinterpret_cast<bf16x8*>(
        &AO[(size_t)(b * SEQ + q0 + qr) * CH + h * 64 + lc * 8]) = v;
  }
}

// ---------------- GEMM2: out = AO @ w_proj + b (fp32 out) ----------------

__global__ __launch_bounds__(256) void gemm_proj(
    const unsigned short* __restrict__ A,   // [8192][1024]
    const unsigned short* __restrict__ Bt,  // [1024][1024]
    const float* __restrict__ bias,
    float* __restrict__ out) {
  __shared__ __align__(16) unsigned short sb[24576];
  int tid = threadIdx.x;
  int lane = tid & 63, wav = tid >> 6;
  int wr = wav >> 1, wc = wav & 1;
  int lr = lane & 15, lh = lane >> 4;
  int m0 = blockIdx.x * 128, n0 = blockIdx.y * 128;

  f32x4 acc[4][4];
  #pragma unroll
  for (int i = 0; i < 4; ++i)
    #pragma unroll
    for (int j = 0; j < 4; ++j)
      acc[i][j] = f32x4{0.f, 0.f, 0.f, 0.f};

  GSTAGE(0, 0)
  GSTAGE(1, 32)
  asm volatile("s_waitcnt vmcnt(4)" ::: "memory");
  __builtin_amdgcn_s_barrier();

  int cur = 0;
  for (int k0 = 0; k0 < 1024; k0 += 32) {
    bool issued = (k0 + 64 < 1024);
    int nb = cur + 2; if (nb >= 3) nb -= 3;
    if (issued) GSTAGE(nb, k0 + 64)
    bf16x8 a[4], b[4];
    #pragma unroll
    for (int i = 0; i < 4; ++i)
      a[i] = *reinterpret_cast<const bf16x8*>(&sb[cur * 4096 + (wr * 64 + i * 16 + lr) * 32 + lh * 8]);
    #pragma unroll
    for (int j = 0; j < 4; ++j)
      b[j] = *reinterpret_cast<const bf16x8*>(&sb[12288 + cur * 4096 + (wc * 64 + j * 16 + lr) * 32 + lh * 8]);
    #pragma unroll
    for (int i = 0; i < 4; ++i)
      #pragma unroll
      for (int j = 0; j < 4; ++j)
        acc[i][j] = __builtin_amdgcn_mfma_f32_16x16x32_bf16(a[i], b[j], acc[i][j], 0, 0, 0);
    if (issued) { asm volatile("s_waitcnt vmcnt(4)" ::: "memory"); }
    else        { asm volatile("s_waitcnt vmcnt(0)" ::: "memory"); }
    __builtin_amdgcn_s_barrier();
    cur = (cur + 1 == 3) ? 0 : cur + 1;
  }

  #pragma unroll
  for (int i = 0; i < 4; ++i) {
    #pragma unroll
    for (int j = 0; j < 4; ++j) {
      int n = n0 + wc * 64 + j * 16 + lr;
      float bv = bias[n];
      #pragma unroll
      for (int r = 0; r < 4; ++r) {
        int m = m0 + wr * 64 + i * 16 + lh * 4 + r;
        out[(size_t)m * 1024 + n] = acc[i][j][r] + bv;
      }
    }
  }
}

// ---------------- launcher ----------------

extern "C" void kernel_launch(void* const* d_in, const int* in_sizes, int n_in,
                              void* d_out, int out_size, void* d_ws, size_t ws_size,
                              hipStream_t stream) {
  const float* x      = (const float*)d_in[0];
  const float* w_attn = (const float*)d_in[1];
  const float* b_attn = (const float*)d_in[2];
  const float* w_proj = (const float*)d_in[3];
  const float* b_proj = (const float*)d_in[4];
  float* out = (float*)d_out;

  char* ws = (char*)d_ws;
  unsigned short* xb  = (unsigned short*)(ws);                       // 16 MB  [8192][1024]
  unsigned short* wAT = (unsigned short*)(ws + 16777216);            // 6 MB   [3072][1024]
  unsigned short* wPT = (unsigned short*)(ws + 23068672);            // 2 MB   [1024][1024]
  unsigned short* Qb  = (unsigned short*)(ws + 25165824);            // 16 MB  [64][2048][64]
  unsigned short* Kb  = (unsigned short*)(ws + 41943040);            // 16 MB
  unsigned short* Vt  = (unsigned short*)(ws + 58720256);            // 16 MB  [64][64][2048]
  unsigned short* AO  = (unsigned short*)(ws + 75497472);            // 16 MB  [8192][1024]

  conv_x_bf16<<<(BT * CH / 4 + 255) / 256, 256, 0, stream>>>(x, xb, BT * CH / 4);
  transpose_w_bf16<<<dim3(3 * CH / 32, CH / 32), dim3(32, 8), 0, stream>>>(w_attn, wAT, CH, 3 * CH);
  transpose_w_bf16<<<dim3(CH / 32, CH / 32), dim3(32, 8), 0, stream>>>(w_proj, wPT, CH, CH);
  gemm_qkv<<<dim3(BT / 128, 3 * CH / 128), 256, 0, stream>>>(xb, wAT, b_attn, Qb, Kb, Vt);
  attn_fwd<<<512, 512, 0, stream>>>(Qb, Kb, Vt, AO);
  gemm_proj<<<dim3(BT / 128, CH / 128), 256, 0, stream>>>(AO, wPT, b_proj, out);
}